// Round 11
// baseline (707.221 us; speedup 1.0000x reference)
//
#include <hip/hip_runtime.h>

// Decoder_36996848287748 v11 — v10 + FFN fused into social kernel.
// Social & FFN share the (n,t)x50-agent token set: post-social residual h
// kept in LDS (fp32 hupd overlaid on dead K/V arena), FFN LN/GEMMs run
// in-block, final h written once. Saves 2 dispatches + ~120MB/layer of h
// traffic. FFN math identical (residual from LDS = same value).
// Social shortcut: agents i>0 attend only to themselves => out_i = v_i (exact).
// MFMA 16x16x32_bf16: A[m=lane&15][k=(lane>>4)*8+e], B[n=lane&15][k=...],
// C[row=(lane>>4)*4+r][col=lane&15] (fp32 accum).

#define DD 128
typedef __attribute__((ext_vector_type(8))) short bf16x8;
typedef __attribute__((ext_vector_type(4))) float f32x4;
#define MFMA16(a, b, c) __builtin_amdgcn_mfma_f32_16x16x32_bf16(a, b, c, 0, 0, 0)

__device__ __forceinline__ float bf2f(unsigned short u) {
  union { unsigned int i; float f; } x; x.i = ((unsigned int)u) << 16; return x.f;
}
__device__ __forceinline__ unsigned short f2bf(float f) {
  union { float f; unsigned int i; } x; x.f = f;
  return (unsigned short)((x.i + 0x7FFFu + ((x.i >> 16) & 1u)) >> 16);
}
__device__ __forceinline__ float wave_sum(float v) {
#pragma unroll
  for (int off = 32; off > 0; off >>= 1) v += __shfl_xor(v, off, 64);
  return v;
}
__device__ __forceinline__ float wave_max(float v) {
#pragma unroll
  for (int off = 32; off > 0; off >>= 1) v = fmaxf(v, __shfl_xor(v, off, 64));
  return v;
}
__device__ __forceinline__ bool load_inv(const void* p, int idx, int bytemode) {
  if (bytemode) return ((const unsigned char*)p)[idx] != 0;
  return ((const int*)p)[idx] != 0;
}

__global__ void detect_kernel(const void* __restrict__ inv, int* __restrict__ flag) {
  __shared__ int found;
  if (threadIdx.x == 0) found = 0;
  __syncthreads();
  const unsigned char* p = (const unsigned char*)inv;
  int loc = 0;
  for (int i = threadIdx.x; i < 16384; i += blockDim.x)
    if ((i & 3) != 0 && p[i] != 0) loc = 1;
  if (loc) atomicOr(&found, 1);
  __syncthreads();
  if (threadIdx.x == 0) *flag = found ? 1 : 0;
}

// Transpose+cvt all weights to bf16 [out][in] via 32x32 LDS tiles. 512 blocks.
__global__ __launch_bounds__(256) void convert_weights(
    const float* __restrict__ Wq, const float* __restrict__ Wk,
    const float* __restrict__ Wv, const float* __restrict__ Wo,
    const float* __restrict__ W1, const float* __restrict__ W2,
    unsigned short* __restrict__ wqkv, unsigned short* __restrict__ wot,
    unsigned short* __restrict__ w1t, unsigned short* __restrict__ w2t) {
  __shared__ float tile[32][33];
  int b = blockIdx.x;
  int tx = threadIdx.x & 31, ty = threadIdx.x >> 5;
  const float* src; unsigned short* dst;
  int o0, i0, srcld, dstld, osub = 0;
  if (b < 192) {                       // Wq/Wk/Wv -> wqkv[m][384][128]
    int m = b / 48, t2 = b % 48;
    o0 = (t2 / 4) * 32; i0 = (t2 % 4) * 32;
    int sel = o0 >> 7;
    src = (sel == 0 ? Wq : (sel == 1 ? Wk : Wv)) + m * 16384;
    osub = sel * 128; srcld = 128;
    dst = wqkv + m * 49152; dstld = 128;
  } else if (b < 256) {                // Wo -> wot[m][128][128]
    int m = (b - 192) / 16, t2 = (b - 192) % 16;
    o0 = (t2 / 4) * 32; i0 = (t2 % 4) * 32;
    src = Wo + m * 16384; srcld = 128;
    dst = wot + m * 16384; dstld = 128;
  } else if (b < 384) {                // W1 [128][512] -> w1t[l][512][128]
    int l = (b - 256) / 64, t2 = (b - 256) % 64;
    o0 = (t2 / 4) * 32; i0 = (t2 % 4) * 32;
    src = W1 + l * 65536; srcld = 512;
    dst = w1t + l * 65536; dstld = 128;
  } else {                             // W2 [512][128] -> w2t[l][128][512]
    int l = (b - 384) / 64, t2 = (b - 384) % 64;
    o0 = (t2 / 16) * 32; i0 = (t2 % 16) * 32;
    src = W2 + l * 65536; srcld = 128;
    dst = w2t + l * 65536; dstld = 512;
  }
#pragma unroll
  for (int kk = 0; kk < 4; ++kk) {
    int i = i0 + ty + 8 * kk, o = o0 + tx;
    tile[ty + 8 * kk][tx] = src[i * srcld + (o - osub)];
  }
  __syncthreads();
#pragma unroll
  for (int kk = 0; kk < 4; ++kk) {
    int o = o0 + ty + 8 * kk, i = i0 + tx;
    dst[o * dstld + i] = f2bf(tile[tx][ty + 8 * kk]);
  }
}

// ---------------- Temporal attention (unchanged from v10) ----------------
__global__ __launch_bounds__(512, 4) void temporal_attn_kernel(
    const float* __restrict__ x, float* __restrict__ h,
    const void* __restrict__ inv, const int* __restrict__ flagp,
    const float* __restrict__ g, const float* __restrict__ bb,
    const float* __restrict__ embW, const float* __restrict__ embB,
    const unsigned short* __restrict__ wqkv,
    const unsigned short* __restrict__ wot, int first) {
  __shared__ __align__(16) unsigned short xbf[64][136];
  __shared__ __align__(16) unsigned short kbf[64][136];
  __shared__ __align__(16) unsigned short vT[128][72];     // V^T [d][tok]
  __shared__ __align__(16) unsigned short pbuf[8][16][72]; // P[tq_loc][tk] per head
  __shared__ float ssb[8][64];
  int seq = blockIdx.x;
  int tid = threadIdx.x, lane = tid & 63, wid = tid >> 6;
  unsigned long long invmask =
      __ballot((lane < 50) && load_inv(inv, seq * 50 + lane, *flagp));
  const f32x4 zf = (f32x4){0.f, 0.f, 0.f, 0.f};
  for (int t = wid; t < 50; t += 8) {
    int tok = seq * 50 + t;
    float x0, x1;
    if (first) {
      float c0 = x[tok * 5], c1 = x[tok * 5 + 1], c2 = x[tok * 5 + 2];
      float c3 = x[tok * 5 + 3], c4 = x[tok * 5 + 4];
      x0 = embB[lane] + c0 * embW[lane] + c1 * embW[128 + lane] +
           c2 * embW[256 + lane] + c3 * embW[384 + lane] + c4 * embW[512 + lane];
      x1 = embB[lane + 64] + c0 * embW[lane + 64] + c1 * embW[128 + lane + 64] +
           c2 * embW[256 + lane + 64] + c3 * embW[384 + lane + 64] +
           c4 * embW[512 + lane + 64];
      h[tok * DD + lane] = x0; h[tok * DD + lane + 64] = x1;
    } else {
      x0 = h[tok * DD + lane]; x1 = h[tok * DD + lane + 64];
    }
    float mu = wave_sum(x0 + x1) * (1.0f / 128.0f);
    float d0 = x0 - mu, d1 = x1 - mu;
    float var = wave_sum(d0 * d0 + d1 * d1) * (1.0f / 128.0f);
    float rstd = rsqrtf(var + 1e-5f);
    xbf[t][lane]      = f2bf(d0 * rstd * g[lane] + bb[lane]);
    xbf[t][lane + 64] = f2bf(d1 * rstd * g[lane + 64] + bb[lane + 64]);
  }
  for (int idx = tid; idx < 1904; idx += 512) {
    int r = idx / 136, cc = idx - r * 136;
    xbf[50 + r][cc] = 0;
    kbf[50 + r][cc] = 0;
  }
  for (int idx = tid; idx < 896; idx += 512) {
    int row = idx / 7, dwi = idx - row * 7;
    ((unsigned int*)&vT[row][50])[dwi] = 0u;
  }
  __syncthreads();
  int lrow = lane & 15, lk = (lane >> 4) * 8, lr4 = (lane >> 4) * 4;
  int colb = wid * 16 + lrow;
  {   // K pass -> kbf
    f32x4 ac[4];
#pragma unroll
    for (int mt = 0; mt < 4; ++mt) ac[mt] = zf;
#pragma unroll
    for (int kt = 0; kt < 4; ++kt) {
      bf16x8 bk = *(const bf16x8*)&wqkv[((8 + wid) * 16 + lrow) * 128 + kt * 32 + lk];
#pragma unroll
      for (int mt = 0; mt < 4; ++mt) {
        bf16x8 a = *(const bf16x8*)&xbf[mt * 16 + lrow][kt * 32 + lk];
        ac[mt] = MFMA16(a, bk, ac[mt]);
      }
    }
#pragma unroll
    for (int mt = 0; mt < 4; ++mt)
#pragma unroll
      for (int r = 0; r < 4; ++r) {
        int row = mt * 16 + lr4 + r;
        if (row < 50) kbf[row][colb] = f2bf(ac[mt][r]);
      }
  }
  {   // V pass -> vT
    f32x4 ac[4];
#pragma unroll
    for (int mt = 0; mt < 4; ++mt) ac[mt] = zf;
#pragma unroll
    for (int kt = 0; kt < 4; ++kt) {
      bf16x8 bv = *(const bf16x8*)&wqkv[((16 + wid) * 16 + lrow) * 128 + kt * 32 + lk];
#pragma unroll
      for (int mt = 0; mt < 4; ++mt) {
        bf16x8 a = *(const bf16x8*)&xbf[mt * 16 + lrow][kt * 32 + lk];
        ac[mt] = MFMA16(a, bv, ac[mt]);
      }
    }
#pragma unroll
    for (int mt = 0; mt < 4; ++mt)
#pragma unroll
      for (int r = 0; r < 4; ++r) {
        int row = mt * 16 + lr4 + r;
        if (row < 50) vT[colb][row] = f2bf(ac[mt][r]);
      }
  }
  {   // Q pass -> xbf overlay
    f32x4 acQ[4];
#pragma unroll
    for (int mt = 0; mt < 4; ++mt) acQ[mt] = zf;
#pragma unroll
    for (int kt = 0; kt < 4; ++kt) {
      bf16x8 bq = *(const bf16x8*)&wqkv[(wid * 16 + lrow) * 128 + kt * 32 + lk];
#pragma unroll
      for (int mt = 0; mt < 4; ++mt) {
        bf16x8 a = *(const bf16x8*)&xbf[mt * 16 + lrow][kt * 32 + lk];
        acQ[mt] = MFMA16(a, bq, acQ[mt]);
      }
    }
    __syncthreads();
#pragma unroll
    for (int mt = 0; mt < 4; ++mt)
#pragma unroll
      for (int r = 0; r < 4; ++r) {
        int row = mt * 16 + lr4 + r;
        if (row < 50) xbf[row][colb] = f2bf(acQ[mt][r] * 0.25f);
      }
  }
  __syncthreads();
  // P3: MFMA attention, LDS-roundtrip P; all deps same-wave
  {
    int hh = wid, c = lane & 15, gq = lane >> 4;
    const int hb = hh * 16;
    bf16x8 vfr0 = *(const bf16x8*)&vT[hb + c][gq * 8];
    bf16x8 vfr1 = *(const bf16x8*)&vT[hb + c][32 + gq * 8];
#pragma unroll
    for (int nt2 = 0; nt2 < 4; ++nt2) {
      bf16x8 qf = (bf16x8){0, 0, 0, 0, 0, 0, 0, 0};
      if (gq < 2) qf = *(const bf16x8*)&xbf[nt2 * 16 + c][hb + gq * 8];
      f32x4 Cs[4];
#pragma unroll
      for (int mt = 0; mt < 4; ++mt) {
        bf16x8 kf = (bf16x8){0, 0, 0, 0, 0, 0, 0, 0};
        if (gq < 2) kf = *(const bf16x8*)&kbf[mt * 16 + c][hb + gq * 8];
        Cs[mt] = MFMA16(kf, qf, zf);
      }
      int tq = nt2 * 16 + c;
      float ss = 0.f;
#pragma unroll
      for (int mt = 0; mt < 4; ++mt) {
        float pv[4];
#pragma unroll
        for (int r = 0; r < 4; ++r) {
          int tk = mt * 16 + gq * 4 + r;
          bool ok = (tk == tq) || ((tk < tq) && !((invmask >> tk) & 1ull));
          float p = ok ? __expf(Cs[mt][r]) : 0.f;
          ss += p;
          pv[r] = p;
        }
        unsigned int* dst = (unsigned int*)&pbuf[hh][c][mt * 16 + gq * 4];
        dst[0] = (unsigned)f2bf(pv[0]) | ((unsigned)f2bf(pv[1]) << 16);
        dst[1] = (unsigned)f2bf(pv[2]) | ((unsigned)f2bf(pv[3]) << 16);
      }
      ss += __shfl_xor(ss, 16, 64);
      ss += __shfl_xor(ss, 32, 64);
      if (gq == 0) ssb[hh][tq] = 1.f / ss;
      asm volatile("s_waitcnt lgkmcnt(0)" ::: "memory");
      __builtin_amdgcn_sched_barrier(0);
      bf16x8 pf0 = *(const bf16x8*)&pbuf[hh][c][gq * 8];
      bf16x8 pf1 = *(const bf16x8*)&pbuf[hh][c][32 + gq * 8];
      f32x4 acO = MFMA16(pf0, vfr0, zf);
      acO = MFMA16(pf1, vfr1, acO);
#pragma unroll
      for (int r = 0; r < 4; ++r) {
        int tqo = nt2 * 16 + gq * 4 + r;
        if (tqo < 50) {
          float rs = ssb[hh][tqo];
          xbf[tqo][hb + c] = f2bf(acO[r] * rs);
        }
      }
    }
  }
  __syncthreads();
  {   // P4: Wo + residual
    f32x4 acc2[4];
#pragma unroll
    for (int mt = 0; mt < 4; ++mt) acc2[mt] = zf;
#pragma unroll
    for (int kt = 0; kt < 4; ++kt) {
      bf16x8 bfr = *(const bf16x8*)&wot[(wid * 16 + lrow) * 128 + kt * 32 + lk];
#pragma unroll
      for (int mt = 0; mt < 4; ++mt) {
        bf16x8 a = *(const bf16x8*)&xbf[mt * 16 + lrow][kt * 32 + lk];
        acc2[mt] = MFMA16(a, bfr, acc2[mt]);
      }
    }
#pragma unroll
    for (int mt = 0; mt < 4; ++mt)
#pragma unroll
      for (int r = 0; r < 4; ++r) {
        int row = mt * 16 + lr4 + r;
        if (row < 50) h[(seq * 50 + row) * DD + colb] += acc2[mt][r];
      }
  }
}

// ---------------- Social + FFN fused ----------------
// 512 thr / 8 waves / (n,t) block. LDS arena 78,976B -> 2 blocks/CU.
__global__ __launch_bounds__(512, 4) void social_ffn_kernel(
    const float* __restrict__ x, float* __restrict__ h,
    const void* __restrict__ inv, const int* __restrict__ flagp,
    const float* __restrict__ dist_emb,
    const float* __restrict__ g, const float* __restrict__ bb,
    const unsigned short* __restrict__ wqkv,
    const unsigned short* __restrict__ wot,
    const float* __restrict__ g2, const float* __restrict__ bb2,
    const unsigned short* __restrict__ w1t, const float* __restrict__ b1,
    const unsigned short* __restrict__ w2t, const float* __restrict__ b2) {
  __shared__ __align__(16) unsigned char arena[78976];
  unsigned short (*xbf)[136] = (unsigned short(*)[136])(arena);           // 17408
  unsigned short (*vsb)[136] = (unsigned short(*)[136])(arena + 17408);   // 17408
  float (*hupd)[132]         = (float(*)[132])(arena);                    // 33792 (overlays xbf+vsb)
  unsigned short (*hid)[520] = (unsigned short(*)[520])(arena + 34816);   // 33280
  unsigned short (*xln)[136] = (unsigned short(*)[136])(arena + 68096);   // 8704
  float* q0s                 = (float*)(arena + 76800);                   // 512
  float (*aw)[52]            = (float(*)[52])(arena + 77312);             // 1664
  int nt_ = blockIdx.x;
  int n = nt_ / 50, t = nt_ - n * 50;
  int tid = threadIdx.x, lane = tid & 63, wid = tid >> 6;
  const f32x4 zf = (f32x4){0.f, 0.f, 0.f, 0.f};
  // --- P1: social LN over strided tokens ---
  for (int j = wid; j < 50; j += 8) {
    int tok = (n * 50 + j) * 50 + t;
    float x0 = h[tok * DD + lane], x1 = h[tok * DD + lane + 64];
    float mu = wave_sum(x0 + x1) * (1.0f / 128.0f);
    float d0 = x0 - mu, d1 = x1 - mu;
    float var = wave_sum(d0 * d0 + d1 * d1) * (1.0f / 128.0f);
    float rstd = rsqrtf(var + 1e-5f);
    xbf[j][lane]      = f2bf(d0 * rstd * g[lane] + bb[lane]);
    xbf[j][lane + 64] = f2bf(d1 * rstd * g[lane + 64] + bb[lane + 64]);
  }
  __syncthreads();
  int lrow = lane & 15, lk = (lane >> 4) * 8, lr4 = (lane >> 4) * 4;
  int colb = wid * 16 + lrow;
  {   // V pass -> vsb
    f32x4 ac[4];
#pragma unroll
    for (int mt = 0; mt < 4; ++mt) ac[mt] = zf;
#pragma unroll
    for (int kt = 0; kt < 4; ++kt) {
      bf16x8 bv = *(const bf16x8*)&wqkv[((16 + wid) * 16 + lrow) * 128 + kt * 32 + lk];
#pragma unroll
      for (int mt = 0; mt < 4; ++mt) {
        bf16x8 a = *(const bf16x8*)&xbf[mt * 16 + lrow][kt * 32 + lk];
        ac[mt] = MFMA16(a, bv, ac[mt]);
      }
    }
#pragma unroll
    for (int mt = 0; mt < 4; ++mt)
#pragma unroll
      for (int r = 0; r < 4; ++r) {
        int row = mt * 16 + lr4 + r;
        if (row < 50) vsb[row][colb] = f2bf(ac[mt][r]);
      }
  }
  {   // Q pass (ego row only) -> q0s
    f32x4 acq = zf;
#pragma unroll
    for (int kt = 0; kt < 4; ++kt) {
      bf16x8 bq = *(const bf16x8*)&wqkv[(wid * 16 + lrow) * 128 + kt * 32 + lk];
      bf16x8 a0 = *(const bf16x8*)&xbf[lrow][kt * 32 + lk];
      acq = MFMA16(a0, bq, acq);
    }
    if (lane < 16) q0s[wid * 16 + lane] = acq[0];
  }
  {   // K pass: compute, sync, overlay into xbf
    f32x4 ac[4];
#pragma unroll
    for (int mt = 0; mt < 4; ++mt) ac[mt] = zf;
#pragma unroll
    for (int kt = 0; kt < 4; ++kt) {
      bf16x8 bk = *(const bf16x8*)&wqkv[((8 + wid) * 16 + lrow) * 128 + kt * 32 + lk];
#pragma unroll
      for (int mt = 0; mt < 4; ++mt) {
        bf16x8 a = *(const bf16x8*)&xbf[mt * 16 + lrow][kt * 32 + lk];
        ac[mt] = MFMA16(a, bk, ac[mt]);
      }
    }
    __syncthreads();
#pragma unroll
    for (int mt = 0; mt < 4; ++mt)
#pragma unroll
      for (int r = 0; r < 4; ++r) {
        int row = mt * 16 + lr4 + r;
        if (row < 50) xbf[row][colb] = f2bf(ac[mt][r]);
      }
  }
  __syncthreads();
  {   // ego softmax; wave = head, lane = agent j
    int hh = wid, j = lane;
    float s = -1e30f;
    if (j < 50) {
      float x0 = x[(n * 2500 + t) * 5 + 0];
      float y0 = x[(n * 2500 + t) * 5 + 1];
      int tokj = (n * 50 + j) * 50 + t;
      float xj = x[tokj * 5 + 0], yj = x[tokj * 5 + 1];
      float dx = x0 - xj, dy = y0 - yj;
      float dist = sqrtf(dx * dx + dy * dy);
      int bucket = (int)(dist / 1.5625f);
      bucket = bucket < 0 ? 0 : (bucket > 31 ? 31 : bucket);
      bool mk = (j != 0) && ((dist > 50.0f) || load_inv(inv, tokj, *flagp));
      bf16x8 k0 = *(const bf16x8*)&xbf[j][hh * 16];
      bf16x8 k1 = *(const bf16x8*)&xbf[j][hh * 16 + 8];
      float acc2 = 0.f;
#pragma unroll
      for (int u = 0; u < 8; ++u)
        acc2 += q0s[hh * 16 + u] * bf2f((unsigned short)k0[u]) +
                q0s[hh * 16 + 8 + u] * bf2f((unsigned short)k1[u]);
      s = mk ? -1e9f : acc2 * 0.25f + dist_emb[bucket * 8 + hh];
    }
    float m = wave_max(s);
    float p = (j < 50) ? __expf(s - m) : 0.f;
    float sm = wave_sum(p);
    if (j < 50) aw[hh][j] = p / sm;
  }
  __syncthreads();
  float a0val = 0.f;
  if (tid < 128) {
    int hh2 = tid >> 4;
#pragma unroll 10
    for (int j = 0; j < 50; ++j) a0val += aw[hh2][j] * bf2f(vsb[j][tid]);
  }
  __syncthreads();
  if (tid < 128) vsb[0][tid] = f2bf(a0val);
  __syncthreads();
  // --- P4: Wo mfma -> regs; then hupd = h_global + attn (LDS only) ---
  {
    f32x4 acc2[4];
#pragma unroll
    for (int mt = 0; mt < 4; ++mt) acc2[mt] = zf;
#pragma unroll
    for (int kt = 0; kt < 4; ++kt) {
      bf16x8 bfr = *(const bf16x8*)&wot[(wid * 16 + lrow) * 128 + kt * 32 + lk];
#pragma unroll
      for (int mt = 0; mt < 4; ++mt) {
        bf16x8 a = *(const bf16x8*)&vsb[mt * 16 + lrow][kt * 32 + lk];
        acc2[mt] = MFMA16(a, bfr, acc2[mt]);
      }
    }
    __syncthreads();   // all xbf/vsb reads done -> arena becomes hupd
#pragma unroll
    for (int mt = 0; mt < 4; ++mt)
#pragma unroll
      for (int r = 0; r < 4; ++r) {
        int row = mt * 16 + lr4 + r;
        if (row < 50) {
          int tok = (n * 50 + row) * 50 + t;
          hupd[row][colb] = h[tok * DD + colb] + acc2[mt][r];
        }
      }
  }
  __syncthreads();
  // --- FFN in two M=32 half-tiles ---
#pragma unroll 1
  for (int h2 = 0; h2 < 2; ++h2) {
    int base2 = h2 * 32;
    // LN2 over hupd rows -> xln (local rows 0..31); zero rows with j>=50
    for (int r2 = wid; r2 < 32; r2 += 8) {
      int j = base2 + r2;
      if (j < 50) {
        float x0 = hupd[j][lane], x1 = hupd[j][lane + 64];
        float mu = wave_sum(x0 + x1) * (1.0f / 128.0f);
        float d0 = x0 - mu, d1 = x1 - mu;
        float var = wave_sum(d0 * d0 + d1 * d1) * (1.0f / 128.0f);
        float rstd = rsqrtf(var + 1e-5f);
        xln[r2][lane]      = f2bf(d0 * rstd * g2[lane] + bb2[lane]);
        xln[r2][lane + 64] = f2bf(d1 * rstd * g2[lane + 64] + bb2[lane + 64]);
      } else {
        xln[r2][lane] = 0;
        xln[r2][lane + 64] = 0;
      }
    }
    __syncthreads();
    // GEMM1: M=32 N=512 K=128; wave owns 64 cols
    {
      f32x4 acc[2][4];
#pragma unroll
      for (int mt = 0; mt < 2; ++mt)
#pragma unroll
        for (int nt = 0; nt < 4; ++nt) acc[mt][nt] = zf;
#pragma unroll
      for (int kt = 0; kt < 4; ++kt) {
        bf16x8 a0 = *(const bf16x8*)&xln[lrow][kt * 32 + lk];
        bf16x8 a1 = *(const bf16x8*)&xln[16 + lrow][kt * 32 + lk];
#pragma unroll
        for (int nt = 0; nt < 4; ++nt) {
          int nn = wid * 64 + nt * 16 + lrow;
          bf16x8 bfr = *(const bf16x8*)&w1t[nn * 128 + kt * 32 + lk];
          acc[0][nt] = MFMA16(a0, bfr, acc[0][nt]);
          acc[1][nt] = MFMA16(a1, bfr, acc[1][nt]);
        }
      }
#pragma unroll
      for (int nt = 0; nt < 4; ++nt) {
        int nn = wid * 64 + nt * 16 + lrow;
        float bias = b1[nn];
#pragma unroll
        for (int mt = 0; mt < 2; ++mt)
#pragma unroll
          for (int r = 0; r < 4; ++r)
            hid[mt * 16 + lr4 + r][nn] = f2bf(fmaxf(acc[mt][nt][r] + bias, 0.f));
      }
    }
    __syncthreads();
    // GEMM2: M=32 N=128 K=512; wave owns 16 cols; final h write
    {
      f32x4 acc2[2];
#pragma unroll
      for (int mt = 0; mt < 2; ++mt) acc2[mt] = zf;
      int nn = wid * 16 + lrow;
#pragma unroll
      for (int kt = 0; kt < 16; ++kt) {
        bf16x8 a0 = *(const bf16x8*)&hid[lrow][kt * 32 + lk];
        bf16x8 a1 = *(const bf16x8*)&hid[16 + lrow][kt * 32 + lk];
        bf16x8 bfr = *(const bf16x8*)&w2t[nn * 512 + kt * 32 + lk];
        acc2[0] = MFMA16(a0, bfr, acc2[0]);
        acc2[1] = MFMA16(a1, bfr, acc2[1]);
      }
      float bias = b2[nn];
#pragma unroll
      for (int mt = 0; mt < 2; ++mt)
#pragma unroll
        for (int r = 0; r < 4; ++r) {
          int j = base2 + mt * 16 + lr4 + r;
          if (j < 50) {
            int tok = (n * 50 + j) * 50 + t;
            h[tok * DD + nn] = hupd[j][nn] + acc2[mt][r] + bias;
          }
        }
    }
    __syncthreads();   // hid/xln reused by next half
  }
}

// Final ego MLP (fp32): 400 blocks x 4 tokens
__global__ __launch_bounds__(256) void ego_mlp_kernel(
    const float* __restrict__ h, const float* __restrict__ W1,
    const float* __restrict__ b1, const float* __restrict__ W2,
    const float* __restrict__ b2, float* __restrict__ out) {
  __shared__ float xr[4][128];
  __shared__ float mid[4][512];
  int base = blockIdx.x * 4;
  int tid = threadIdx.x;
  for (int idx = tid; idx < 512; idx += 256) {
    int r = idx >> 7, dd = idx & 127;
    int nt = base + r, n = nt / 50, t = nt - n * 50;
    xr[r][dd] = h[(n * 2500 + t) * DD + dd];
  }
  __syncthreads();
  {
    int f = tid;
    float a0[4], a1[4];
#pragma unroll
    for (int r = 0; r < 4; ++r) { a0[r] = b1[f]; a1[r] = b1[f + 256]; }
    for (int c = 0; c < 128; ++c) {
      float w0 = W1[c * 512 + f], w1 = W1[c * 512 + f + 256];
#pragma unroll
      for (int r = 0; r < 4; ++r) {
        float xv = xr[r][c];
        a0[r] += xv * w0;
        a1[r] += xv * w1;
      }
    }
#pragma unroll
    for (int r = 0; r < 4; ++r) { mid[r][f] = a0[r]; mid[r][f + 256] = a1[r]; }
  }
  __syncthreads();
  for (int idx = tid; idx < 480; idx += 256) {
    int r = idx / 120, p = idx - r * 120;
    float acc = b2[p];
    for (int f2 = 0; f2 < 512; ++f2) acc += mid[r][f2] * W2[f2 * 120 + p];
    out[(base + r) * 120 + p] = acc;
  }
}

extern "C" void kernel_launch(void* const* d_in, const int* in_sizes, int n_in,
                              void* d_out, int out_size, void* d_ws, size_t ws_size,
                              hipStream_t stream) {
  const float* x        = (const float*)d_in[0];
  const void*  inv      = d_in[1];
  const float* emb_W    = (const float*)d_in[2];
  const float* emb_b    = (const float*)d_in[3];
  const float* dist_emb = (const float*)d_in[4];
  const float* ln_g     = (const float*)d_in[5];
  const float* ln_b     = (const float*)d_in[6];
  const float* Wq       = (const float*)d_in[7];
  const float* Wk       = (const float*)d_in[8];
  const float* Wv       = (const float*)d_in[9];
  const float* Wo       = (const float*)d_in[10];
  const float* ffn_W1   = (const float*)d_in[11];
  const float* ffn_b1   = (const float*)d_in[12];
  const float* ffn_W2   = (const float*)d_in[13];
  const float* ffn_b2   = (const float*)d_in[14];
  const float* mlp_W1   = (const float*)d_in[15];
  const float* mlp_b1   = (const float*)d_in[16];
  const float* mlp_W2   = (const float*)d_in[17];
  const float* mlp_b2   = (const float*)d_in[18];
  float* out = (float*)d_out;

  float* ws = (float*)d_ws;
  float* h  = ws;                                        // 10,240,000 floats
  unsigned short* wbf = (unsigned short*)(ws + 10240000);
  unsigned short* wqkv = wbf;                            // 196608
  unsigned short* wot  = wbf + 196608;                   // 65536
  unsigned short* w1t  = wbf + 262144;                   // 131072
  unsigned short* w2t  = wbf + 393216;                   // 131072
  int* flag = (int*)(ws + 10600000);

  detect_kernel<<<dim3(1), dim3(256), 0, stream>>>(inv, flag);
  convert_weights<<<dim3(512), dim3(256), 0, stream>>>(Wq, Wk, Wv, Wo, ffn_W1,
                                                       ffn_W2, wqkv, wot, w1t, w2t);
  for (int l = 0; l < 2; ++l) {
    temporal_attn_kernel<<<dim3(1600), dim3(512), 0, stream>>>(
        x, h, inv, flag, ln_g + (l * 3 + 0) * DD, ln_b + (l * 3 + 0) * DD,
        emb_W, emb_b, wqkv + (l * 2 + 0) * 49152, wot + (l * 2 + 0) * 16384,
        l == 0 ? 1 : 0);
    social_ffn_kernel<<<dim3(1600), dim3(512), 0, stream>>>(
        x, h, inv, flag, dist_emb,
        ln_g + (l * 3 + 1) * DD, ln_b + (l * 3 + 1) * DD,
        wqkv + (l * 2 + 1) * 49152, wot + (l * 2 + 1) * 16384,
        ln_g + (l * 3 + 2) * DD, ln_b + (l * 3 + 2) * DD,
        w1t + l * 65536, ffn_b1 + l * 512, w2t + l * 65536, ffn_b2 + l * 128);
  }
  ego_mlp_kernel<<<dim3(400), dim3(256), 0, stream>>>(h, mlp_W1, mlp_b1,
                                                      mlp_W2, mlp_b2, out);
}

// Round 12
// 400.688 us; speedup vs baseline: 1.7650x; 1.7650x over previous
//
#include <hip/hip_runtime.h>

// Decoder_36996848287748 v12 — v10 base (v11 fusion reverted: 680MB/dispatch
// HBM blowup) + dead-code cut: output = h[:,0] only, so
//   * ffn_1 computed only for agent-0 tokens (1600 vs 80000), fused with ego MLP
//   * social_1 runs ego_only: Wo + h-write for row 0 only
// Ego MLP now bf16 MFMA (budget: +~1e-3 on 6.8e-3 threshold, 3.5x headroom).
// Social shortcut: agents i>0 attend only to themselves => out_i = v_i (exact).
// MFMA 16x16x32_bf16: A[m=lane&15][k=(lane>>4)*8+e], B[n=lane&15][k=...],
// C[row=(lane>>4)*4+r][col=lane&15] (fp32 accum).

#define DD 128
typedef __attribute__((ext_vector_type(8))) short bf16x8;
typedef __attribute__((ext_vector_type(4))) float f32x4;
#define MFMA16(a, b, c) __builtin_amdgcn_mfma_f32_16x16x32_bf16(a, b, c, 0, 0, 0)

__device__ __forceinline__ float bf2f(unsigned short u) {
  union { unsigned int i; float f; } x; x.i = ((unsigned int)u) << 16; return x.f;
}
__device__ __forceinline__ unsigned short f2bf(float f) {
  union { float f; unsigned int i; } x; x.f = f;
  return (unsigned short)((x.i + 0x7FFFu + ((x.i >> 16) & 1u)) >> 16);
}
__device__ __forceinline__ float wave_sum(float v) {
#pragma unroll
  for (int off = 32; off > 0; off >>= 1) v += __shfl_xor(v, off, 64);
  return v;
}
__device__ __forceinline__ float wave_max(float v) {
#pragma unroll
  for (int off = 32; off > 0; off >>= 1) v = fmaxf(v, __shfl_xor(v, off, 64));
  return v;
}
__device__ __forceinline__ bool load_inv(const void* p, int idx, int bytemode) {
  if (bytemode) return ((const unsigned char*)p)[idx] != 0;
  return ((const int*)p)[idx] != 0;
}

__global__ void detect_kernel(const void* __restrict__ inv, int* __restrict__ flag) {
  __shared__ int found;
  if (threadIdx.x == 0) found = 0;
  __syncthreads();
  const unsigned char* p = (const unsigned char*)inv;
  int loc = 0;
  for (int i = threadIdx.x; i < 16384; i += blockDim.x)
    if ((i & 3) != 0 && p[i] != 0) loc = 1;
  if (loc) atomicOr(&found, 1);
  __syncthreads();
  if (threadIdx.x == 0) *flag = found ? 1 : 0;
}

// Transpose+cvt weights to bf16 [out][in] via 32x32 LDS tiles. 640 blocks.
__global__ __launch_bounds__(256) void convert_weights(
    const float* __restrict__ Wq, const float* __restrict__ Wk,
    const float* __restrict__ Wv, const float* __restrict__ Wo,
    const float* __restrict__ W1, const float* __restrict__ W2,
    const float* __restrict__ W1m, const float* __restrict__ W2m,
    unsigned short* __restrict__ wqkv, unsigned short* __restrict__ wot,
    unsigned short* __restrict__ w1t, unsigned short* __restrict__ w2t,
    unsigned short* __restrict__ w1e, unsigned short* __restrict__ w2e) {
  __shared__ float tile[32][33];
  int b = blockIdx.x;
  int tx = threadIdx.x & 31, ty = threadIdx.x >> 5;
  const float* src; unsigned short* dst;
  int o0, i0, srcld, dstld, osub = 0, obound = 1 << 30;
  if (b < 192) {                       // Wq/Wk/Wv -> wqkv[m][384][128]
    int m = b / 48, t2 = b % 48;
    o0 = (t2 / 4) * 32; i0 = (t2 % 4) * 32;
    int sel = o0 >> 7;
    src = (sel == 0 ? Wq : (sel == 1 ? Wk : Wv)) + m * 16384;
    osub = sel * 128; srcld = 128;
    dst = wqkv + m * 49152; dstld = 128;
  } else if (b < 256) {                // Wo -> wot[m][128][128]
    int m = (b - 192) / 16, t2 = (b - 192) % 16;
    o0 = (t2 / 4) * 32; i0 = (t2 % 4) * 32;
    src = Wo + m * 16384; srcld = 128;
    dst = wot + m * 16384; dstld = 128;
  } else if (b < 384) {                // W1 [128][512] -> w1t[l][512][128]
    int l = (b - 256) / 64, t2 = (b - 256) % 64;
    o0 = (t2 / 4) * 32; i0 = (t2 % 4) * 32;
    src = W1 + l * 65536; srcld = 512;
    dst = w1t + l * 65536; dstld = 128;
  } else if (b < 512) {                // W2 [512][128] -> w2t[l][128][512]
    int l = (b - 384) / 64, t2 = (b - 384) % 64;
    o0 = (t2 / 16) * 32; i0 = (t2 % 16) * 32;
    src = W2 + l * 65536; srcld = 128;
    dst = w2t + l * 65536; dstld = 512;
  } else if (b < 576) {                // mlp_W1 [128][512] -> w1e[512][128]
    int t2 = b - 512;
    o0 = (t2 / 4) * 32; i0 = (t2 % 4) * 32;
    src = W1m; srcld = 512;
    dst = w1e; dstld = 128;
  } else {                             // mlp_W2 [512][120] -> w2e[128][512] pad0
    int t2 = b - 576;
    o0 = (t2 / 16) * 32; i0 = (t2 % 16) * 32;
    src = W2m; srcld = 120; obound = 120;
    dst = w2e; dstld = 512;
  }
#pragma unroll
  for (int kk = 0; kk < 4; ++kk) {
    int i = i0 + ty + 8 * kk, o = o0 + tx;
    tile[ty + 8 * kk][tx] = (o < obound) ? src[i * srcld + (o - osub)] : 0.f;
  }
  __syncthreads();
#pragma unroll
  for (int kk = 0; kk < 4; ++kk) {
    int o = o0 + ty + 8 * kk, i = i0 + tx;
    dst[o * dstld + i] = f2bf(tile[tx][ty + 8 * kk]);
  }
}

// ---------------- Temporal attention (unchanged from v10) ----------------
__global__ __launch_bounds__(512, 4) void temporal_attn_kernel(
    const float* __restrict__ x, float* __restrict__ h,
    const void* __restrict__ inv, const int* __restrict__ flagp,
    const float* __restrict__ g, const float* __restrict__ bb,
    const float* __restrict__ embW, const float* __restrict__ embB,
    const unsigned short* __restrict__ wqkv,
    const unsigned short* __restrict__ wot, int first) {
  __shared__ __align__(16) unsigned short xbf[64][136];
  __shared__ __align__(16) unsigned short kbf[64][136];
  __shared__ __align__(16) unsigned short vT[128][72];     // V^T [d][tok]
  __shared__ __align__(16) unsigned short pbuf[8][16][72]; // P[tq_loc][tk] per head
  __shared__ float ssb[8][64];
  int seq = blockIdx.x;
  int tid = threadIdx.x, lane = tid & 63, wid = tid >> 6;
  unsigned long long invmask =
      __ballot((lane < 50) && load_inv(inv, seq * 50 + lane, *flagp));
  const f32x4 zf = (f32x4){0.f, 0.f, 0.f, 0.f};
  for (int t = wid; t < 50; t += 8) {
    int tok = seq * 50 + t;
    float x0, x1;
    if (first) {
      float c0 = x[tok * 5], c1 = x[tok * 5 + 1], c2 = x[tok * 5 + 2];
      float c3 = x[tok * 5 + 3], c4 = x[tok * 5 + 4];
      x0 = embB[lane] + c0 * embW[lane] + c1 * embW[128 + lane] +
           c2 * embW[256 + lane] + c3 * embW[384 + lane] + c4 * embW[512 + lane];
      x1 = embB[lane + 64] + c0 * embW[lane + 64] + c1 * embW[128 + lane + 64] +
           c2 * embW[256 + lane + 64] + c3 * embW[384 + lane + 64] +
           c4 * embW[512 + lane + 64];
      h[tok * DD + lane] = x0; h[tok * DD + lane + 64] = x1;
    } else {
      x0 = h[tok * DD + lane]; x1 = h[tok * DD + lane + 64];
    }
    float mu = wave_sum(x0 + x1) * (1.0f / 128.0f);
    float d0 = x0 - mu, d1 = x1 - mu;
    float var = wave_sum(d0 * d0 + d1 * d1) * (1.0f / 128.0f);
    float rstd = rsqrtf(var + 1e-5f);
    xbf[t][lane]      = f2bf(d0 * rstd * g[lane] + bb[lane]);
    xbf[t][lane + 64] = f2bf(d1 * rstd * g[lane + 64] + bb[lane + 64]);
  }
  for (int idx = tid; idx < 1904; idx += 512) {
    int r = idx / 136, cc = idx - r * 136;
    xbf[50 + r][cc] = 0;
    kbf[50 + r][cc] = 0;
  }
  for (int idx = tid; idx < 896; idx += 512) {
    int row = idx / 7, dwi = idx - row * 7;
    ((unsigned int*)&vT[row][50])[dwi] = 0u;
  }
  __syncthreads();
  int lrow = lane & 15, lk = (lane >> 4) * 8, lr4 = (lane >> 4) * 4;
  int colb = wid * 16 + lrow;
  {   // K pass -> kbf
    f32x4 ac[4];
#pragma unroll
    for (int mt = 0; mt < 4; ++mt) ac[mt] = zf;
#pragma unroll
    for (int kt = 0; kt < 4; ++kt) {
      bf16x8 bk = *(const bf16x8*)&wqkv[((8 + wid) * 16 + lrow) * 128 + kt * 32 + lk];
#pragma unroll
      for (int mt = 0; mt < 4; ++mt) {
        bf16x8 a = *(const bf16x8*)&xbf[mt * 16 + lrow][kt * 32 + lk];
        ac[mt] = MFMA16(a, bk, ac[mt]);
      }
    }
#pragma unroll
    for (int mt = 0; mt < 4; ++mt)
#pragma unroll
      for (int r = 0; r < 4; ++r) {
        int row = mt * 16 + lr4 + r;
        if (row < 50) kbf[row][colb] = f2bf(ac[mt][r]);
      }
  }
  {   // V pass -> vT
    f32x4 ac[4];
#pragma unroll
    for (int mt = 0; mt < 4; ++mt) ac[mt] = zf;
#pragma unroll
    for (int kt = 0; kt < 4; ++kt) {
      bf16x8 bv = *(const bf16x8*)&wqkv[((16 + wid) * 16 + lrow) * 128 + kt * 32 + lk];
#pragma unroll
      for (int mt = 0; mt < 4; ++mt) {
        bf16x8 a = *(const bf16x8*)&xbf[mt * 16 + lrow][kt * 32 + lk];
        ac[mt] = MFMA16(a, bv, ac[mt]);
      }
    }
#pragma unroll
    for (int mt = 0; mt < 4; ++mt)
#pragma unroll
      for (int r = 0; r < 4; ++r) {
        int row = mt * 16 + lr4 + r;
        if (row < 50) vT[colb][row] = f2bf(ac[mt][r]);
      }
  }
  {   // Q pass -> xbf overlay
    f32x4 acQ[4];
#pragma unroll
    for (int mt = 0; mt < 4; ++mt) acQ[mt] = zf;
#pragma unroll
    for (int kt = 0; kt < 4; ++kt) {
      bf16x8 bq = *(const bf16x8*)&wqkv[(wid * 16 + lrow) * 128 + kt * 32 + lk];
#pragma unroll
      for (int mt = 0; mt < 4; ++mt) {
        bf16x8 a = *(const bf16x8*)&xbf[mt * 16 + lrow][kt * 32 + lk];
        acQ[mt] = MFMA16(a, bq, acQ[mt]);
      }
    }
    __syncthreads();
#pragma unroll
    for (int mt = 0; mt < 4; ++mt)
#pragma unroll
      for (int r = 0; r < 4; ++r) {
        int row = mt * 16 + lr4 + r;
        if (row < 50) xbf[row][colb] = f2bf(acQ[mt][r] * 0.25f);
      }
  }
  __syncthreads();
  // P3: MFMA attention, LDS-roundtrip P; all deps same-wave
  {
    int hh = wid, c = lane & 15, gq = lane >> 4;
    const int hb = hh * 16;
    bf16x8 vfr0 = *(const bf16x8*)&vT[hb + c][gq * 8];
    bf16x8 vfr1 = *(const bf16x8*)&vT[hb + c][32 + gq * 8];
#pragma unroll
    for (int nt2 = 0; nt2 < 4; ++nt2) {
      bf16x8 qf = (bf16x8){0, 0, 0, 0, 0, 0, 0, 0};
      if (gq < 2) qf = *(const bf16x8*)&xbf[nt2 * 16 + c][hb + gq * 8];
      f32x4 Cs[4];
#pragma unroll
      for (int mt = 0; mt < 4; ++mt) {
        bf16x8 kf = (bf16x8){0, 0, 0, 0, 0, 0, 0, 0};
        if (gq < 2) kf = *(const bf16x8*)&kbf[mt * 16 + c][hb + gq * 8];
        Cs[mt] = MFMA16(kf, qf, zf);
      }
      int tq = nt2 * 16 + c;
      float ss = 0.f;
#pragma unroll
      for (int mt = 0; mt < 4; ++mt) {
        float pv[4];
#pragma unroll
        for (int r = 0; r < 4; ++r) {
          int tk = mt * 16 + gq * 4 + r;
          bool ok = (tk == tq) || ((tk < tq) && !((invmask >> tk) & 1ull));
          float p = ok ? __expf(Cs[mt][r]) : 0.f;
          ss += p;
          pv[r] = p;
        }
        unsigned int* dst = (unsigned int*)&pbuf[hh][c][mt * 16 + gq * 4];
        dst[0] = (unsigned)f2bf(pv[0]) | ((unsigned)f2bf(pv[1]) << 16);
        dst[1] = (unsigned)f2bf(pv[2]) | ((unsigned)f2bf(pv[3]) << 16);
      }
      ss += __shfl_xor(ss, 16, 64);
      ss += __shfl_xor(ss, 32, 64);
      if (gq == 0) ssb[hh][tq] = 1.f / ss;
      asm volatile("s_waitcnt lgkmcnt(0)" ::: "memory");
      __builtin_amdgcn_sched_barrier(0);
      bf16x8 pf0 = *(const bf16x8*)&pbuf[hh][c][gq * 8];
      bf16x8 pf1 = *(const bf16x8*)&pbuf[hh][c][32 + gq * 8];
      f32x4 acO = MFMA16(pf0, vfr0, zf);
      acO = MFMA16(pf1, vfr1, acO);
#pragma unroll
      for (int r = 0; r < 4; ++r) {
        int tqo = nt2 * 16 + gq * 4 + r;
        if (tqo < 50) {
          float rs = ssb[hh][tqo];
          xbf[tqo][hb + c] = f2bf(acO[r] * rs);
        }
      }
    }
  }
  __syncthreads();
  {   // P4: Wo + residual
    f32x4 acc2[4];
#pragma unroll
    for (int mt = 0; mt < 4; ++mt) acc2[mt] = zf;
#pragma unroll
    for (int kt = 0; kt < 4; ++kt) {
      bf16x8 bfr = *(const bf16x8*)&wot[(wid * 16 + lrow) * 128 + kt * 32 + lk];
#pragma unroll
      for (int mt = 0; mt < 4; ++mt) {
        bf16x8 a = *(const bf16x8*)&xbf[mt * 16 + lrow][kt * 32 + lk];
        acc2[mt] = MFMA16(a, bfr, acc2[mt]);
      }
    }
#pragma unroll
    for (int mt = 0; mt < 4; ++mt)
#pragma unroll
      for (int r = 0; r < 4; ++r) {
        int row = mt * 16 + lr4 + r;
        if (row < 50) h[(seq * 50 + row) * DD + colb] += acc2[mt][r];
      }
  }
}

// ---------------- Social attention (v10 + ego_only mode) ----------------
__global__ __launch_bounds__(512, 6) void social_attn_kernel(
    const float* __restrict__ x, float* __restrict__ h,
    const void* __restrict__ inv, const int* __restrict__ flagp,
    const float* __restrict__ dist_emb,
    const float* __restrict__ g, const float* __restrict__ bb,
    const unsigned short* __restrict__ wqkv,
    const unsigned short* __restrict__ wot, int ego_only) {
  __shared__ __align__(16) unsigned short xbf[64][136];  // LN-out -> K overlay
  __shared__ __align__(16) unsigned short vsb[64][136];  // V; row0 -> ego attn
  __shared__ float q0s[128];
  __shared__ float aw[8][52];
  int nt_ = blockIdx.x;
  int n = nt_ / 50, t = nt_ - n * 50;
  int tid = threadIdx.x, lane = tid & 63, wid = tid >> 6;
  const f32x4 zf = (f32x4){0.f, 0.f, 0.f, 0.f};
  for (int j = wid; j < 50; j += 8) {
    int tok = (n * 50 + j) * 50 + t;
    float x0 = h[tok * DD + lane], x1 = h[tok * DD + lane + 64];
    float mu = wave_sum(x0 + x1) * (1.0f / 128.0f);
    float d0 = x0 - mu, d1 = x1 - mu;
    float var = wave_sum(d0 * d0 + d1 * d1) * (1.0f / 128.0f);
    float rstd = rsqrtf(var + 1e-5f);
    xbf[j][lane]      = f2bf(d0 * rstd * g[lane] + bb[lane]);
    xbf[j][lane + 64] = f2bf(d1 * rstd * g[lane + 64] + bb[lane + 64]);
  }
  __syncthreads();
  int lrow = lane & 15, lk = (lane >> 4) * 8, lr4 = (lane >> 4) * 4;
  int colb = wid * 16 + lrow;
  {   // V pass -> vsb
    f32x4 ac[4];
#pragma unroll
    for (int mt = 0; mt < 4; ++mt) ac[mt] = zf;
#pragma unroll
    for (int kt = 0; kt < 4; ++kt) {
      bf16x8 bv = *(const bf16x8*)&wqkv[((16 + wid) * 16 + lrow) * 128 + kt * 32 + lk];
#pragma unroll
      for (int mt = 0; mt < 4; ++mt) {
        bf16x8 a = *(const bf16x8*)&xbf[mt * 16 + lrow][kt * 32 + lk];
        ac[mt] = MFMA16(a, bv, ac[mt]);
      }
    }
#pragma unroll
    for (int mt = 0; mt < 4; ++mt)
#pragma unroll
      for (int r = 0; r < 4; ++r) {
        int row = mt * 16 + lr4 + r;
        if (row < 50) vsb[row][colb] = f2bf(ac[mt][r]);
      }
  }
  {   // Q pass (ego row only) -> q0s
    f32x4 acq = zf;
#pragma unroll
    for (int kt = 0; kt < 4; ++kt) {
      bf16x8 bq = *(const bf16x8*)&wqkv[(wid * 16 + lrow) * 128 + kt * 32 + lk];
      bf16x8 a0 = *(const bf16x8*)&xbf[lrow][kt * 32 + lk];
      acq = MFMA16(a0, bq, acq);
    }
    if (lane < 16) q0s[wid * 16 + lane] = acq[0];
  }
  {   // K pass: compute, sync, overlay into xbf
    f32x4 ac[4];
#pragma unroll
    for (int mt = 0; mt < 4; ++mt) ac[mt] = zf;
#pragma unroll
    for (int kt = 0; kt < 4; ++kt) {
      bf16x8 bk = *(const bf16x8*)&wqkv[((8 + wid) * 16 + lrow) * 128 + kt * 32 + lk];
#pragma unroll
      for (int mt = 0; mt < 4; ++mt) {
        bf16x8 a = *(const bf16x8*)&xbf[mt * 16 + lrow][kt * 32 + lk];
        ac[mt] = MFMA16(a, bk, ac[mt]);
      }
    }
    __syncthreads();
#pragma unroll
    for (int mt = 0; mt < 4; ++mt)
#pragma unroll
      for (int r = 0; r < 4; ++r) {
        int row = mt * 16 + lr4 + r;
        if (row < 50) xbf[row][colb] = f2bf(ac[mt][r]);
      }
  }
  __syncthreads();
  {   // ego softmax; wave = head, lane = agent j
    int hh = wid, j = lane;
    float s = -1e30f;
    if (j < 50) {
      float x0 = x[(n * 2500 + t) * 5 + 0];
      float y0 = x[(n * 2500 + t) * 5 + 1];
      int tokj = (n * 50 + j) * 50 + t;
      float xj = x[tokj * 5 + 0], yj = x[tokj * 5 + 1];
      float dx = x0 - xj, dy = y0 - yj;
      float dist = sqrtf(dx * dx + dy * dy);
      int bucket = (int)(dist / 1.5625f);
      bucket = bucket < 0 ? 0 : (bucket > 31 ? 31 : bucket);
      bool mk = (j != 0) && ((dist > 50.0f) || load_inv(inv, tokj, *flagp));
      bf16x8 k0 = *(const bf16x8*)&xbf[j][hh * 16];
      bf16x8 k1 = *(const bf16x8*)&xbf[j][hh * 16 + 8];
      float acc2 = 0.f;
#pragma unroll
      for (int u = 0; u < 8; ++u)
        acc2 += q0s[hh * 16 + u] * bf2f((unsigned short)k0[u]) +
                q0s[hh * 16 + 8 + u] * bf2f((unsigned short)k1[u]);
      s = mk ? -1e9f : acc2 * 0.25f + dist_emb[bucket * 8 + hh];
    }
    float m = wave_max(s);
    float p = (j < 50) ? __expf(s - m) : 0.f;
    float sm = wave_sum(p);
    if (j < 50) aw[hh][j] = p / sm;
  }
  __syncthreads();
  float a0val = 0.f;
  if (tid < 128) {
    int hh2 = tid >> 4;
#pragma unroll 10
    for (int j = 0; j < 50; ++j) a0val += aw[hh2][j] * bf2f(vsb[j][tid]);
  }
  __syncthreads();
  if (tid < 128) vsb[0][tid] = f2bf(a0val);
  __syncthreads();
  if (!ego_only) {   // Wo + residual, all rows
    f32x4 acc2[4];
#pragma unroll
    for (int mt = 0; mt < 4; ++mt) acc2[mt] = zf;
#pragma unroll
    for (int kt = 0; kt < 4; ++kt) {
      bf16x8 bfr = *(const bf16x8*)&wot[(wid * 16 + lrow) * 128 + kt * 32 + lk];
#pragma unroll
      for (int mt = 0; mt < 4; ++mt) {
        bf16x8 a = *(const bf16x8*)&vsb[mt * 16 + lrow][kt * 32 + lk];
        acc2[mt] = MFMA16(a, bfr, acc2[mt]);
      }
    }
#pragma unroll
    for (int mt = 0; mt < 4; ++mt)
#pragma unroll
      for (int r = 0; r < 4; ++r) {
        int row = mt * 16 + lr4 + r;
        if (row < 50)
          h[((n * 50 + row) * 50 + t) * DD + colb] += acc2[mt][r];
      }
  } else {           // Wo + residual for row 0 only (m-tile 0)
    f32x4 acc2 = zf;
#pragma unroll
    for (int kt = 0; kt < 4; ++kt) {
      bf16x8 bfr = *(const bf16x8*)&wot[(wid * 16 + lrow) * 128 + kt * 32 + lk];
      bf16x8 a = *(const bf16x8*)&vsb[lrow][kt * 32 + lk];
      acc2 = MFMA16(a, bfr, acc2);
    }
    if ((lane >> 4) == 0)   // C row 0 = (lane>>4)*4 + 0
      h[(n * 2500 + t) * DD + colb] += acc2[0];
  }
}

// ---------------- FFN (v10, layer 0 only) ----------------
__global__ __launch_bounds__(512, 6) void ffn_kernel(
    float* __restrict__ h, const float* __restrict__ g, const float* __restrict__ bb,
    const unsigned short* __restrict__ w1t, const float* __restrict__ b1,
    const unsigned short* __restrict__ w2t, const float* __restrict__ b2) {
  __shared__ __align__(16) unsigned short xbf[32][136];
  __shared__ __align__(16) unsigned short hid[32][520];
  int base = blockIdx.x * 32;
  int tid = threadIdx.x, lane = tid & 63, wid = tid >> 6;
  for (int r = wid; r < 32; r += 8) {
    int tok = base + r;
    float x0 = h[tok * DD + lane], x1 = h[tok * DD + lane + 64];
    float mu = wave_sum(x0 + x1) * (1.0f / 128.0f);
    float d0 = x0 - mu, d1 = x1 - mu;
    float var = wave_sum(d0 * d0 + d1 * d1) * (1.0f / 128.0f);
    float rstd = rsqrtf(var + 1e-5f);
    xbf[r][lane]      = f2bf(d0 * rstd * g[lane] + bb[lane]);
    xbf[r][lane + 64] = f2bf(d1 * rstd * g[lane + 64] + bb[lane + 64]);
  }
  __syncthreads();
  int lrow = lane & 15, lk = (lane >> 4) * 8, lr4 = (lane >> 4) * 4;
  {
    f32x4 acc[2][4];
#pragma unroll
    for (int mt = 0; mt < 2; ++mt)
#pragma unroll
      for (int nt = 0; nt < 4; ++nt) acc[mt][nt] = (f32x4){0.f, 0.f, 0.f, 0.f};
#pragma unroll
    for (int kt = 0; kt < 4; ++kt) {
      bf16x8 a0 = *(const bf16x8*)&xbf[lrow][kt * 32 + lk];
      bf16x8 a1 = *(const bf16x8*)&xbf[16 + lrow][kt * 32 + lk];
#pragma unroll
      for (int nt = 0; nt < 4; ++nt) {
        int nn = wid * 64 + nt * 16 + lrow;
        bf16x8 bfr = *(const bf16x8*)&w1t[nn * 128 + kt * 32 + lk];
        acc[0][nt] = MFMA16(a0, bfr, acc[0][nt]);
        acc[1][nt] = MFMA16(a1, bfr, acc[1][nt]);
      }
    }
#pragma unroll
    for (int nt = 0; nt < 4; ++nt) {
      int nn = wid * 64 + nt * 16 + lrow;
      float bias = b1[nn];
#pragma unroll
      for (int mt = 0; mt < 2; ++mt)
#pragma unroll
        for (int r = 0; r < 4; ++r)
          hid[mt * 16 + lr4 + r][nn] = f2bf(fmaxf(acc[mt][nt][r] + bias, 0.f));
    }
  }
  __syncthreads();
  {
    f32x4 acc2[2];
#pragma unroll
    for (int mt = 0; mt < 2; ++mt) acc2[mt] = (f32x4){0.f, 0.f, 0.f, 0.f};
    int nn = wid * 16 + lrow;
#pragma unroll
    for (int kt = 0; kt < 16; ++kt) {
      bf16x8 a0 = *(const bf16x8*)&hid[lrow][kt * 32 + lk];
      bf16x8 a1 = *(const bf16x8*)&hid[16 + lrow][kt * 32 + lk];
      bf16x8 bfr = *(const bf16x8*)&w2t[nn * 512 + kt * 32 + lk];
      acc2[0] = MFMA16(a0, bfr, acc2[0]);
      acc2[1] = MFMA16(a1, bfr, acc2[1]);
    }
    float bias = b2[nn];
#pragma unroll
    for (int mt = 0; mt < 2; ++mt)
#pragma unroll
      for (int r = 0; r < 4; ++r)
        h[(base + mt * 16 + lr4 + r) * DD + nn] += acc2[mt][r] + bias;
  }
}

// ---------------- Fused layer-1 FFN (agent-0 only) + ego MLP ----------------
// 100 blocks x 16 tokens, 256 thr / 4 waves. All MFMA. LDS ~29.4KB.
__global__ __launch_bounds__(256) void ffn_ego_kernel(
    const float* __restrict__ h,
    const float* __restrict__ g2, const float* __restrict__ bb2,
    const unsigned short* __restrict__ w1t, const float* __restrict__ b1,
    const unsigned short* __restrict__ w2t, const float* __restrict__ b2,
    const unsigned short* __restrict__ w1e, const float* __restrict__ b1m,
    const unsigned short* __restrict__ w2e, const float* __restrict__ b2m,
    float* __restrict__ out) {
  __shared__ float hx[16][132];                       // residual (fp32)
  __shared__ __align__(16) unsigned short xln[16][136]; // LN out -> e overlay
  __shared__ __align__(16) unsigned short hid[16][520]; // ffn hidden -> mlp mid
  int base = blockIdx.x * 16;
  int tid = threadIdx.x, lane = tid & 63, wid = tid >> 6;
  const f32x4 zf = (f32x4){0.f, 0.f, 0.f, 0.f};
  for (int idx = tid; idx < 2048; idx += 256) {
    int r = idx >> 7, d = idx & 127;
    int nt = base + r, n = nt / 50, t = nt - n * 50;
    hx[r][d] = h[(n * 2500 + t) * DD + d];
  }
  __syncthreads();
  for (int r = wid; r < 16; r += 4) {    // LN2
    float x0 = hx[r][lane], x1 = hx[r][lane + 64];
    float mu = wave_sum(x0 + x1) * (1.0f / 128.0f);
    float d0 = x0 - mu, d1 = x1 - mu;
    float var = wave_sum(d0 * d0 + d1 * d1) * (1.0f / 128.0f);
    float rstd = rsqrtf(var + 1e-5f);
    xln[r][lane]      = f2bf(d0 * rstd * g2[lane] + bb2[lane]);
    xln[r][lane + 64] = f2bf(d1 * rstd * g2[lane + 64] + bb2[lane + 64]);
  }
  __syncthreads();
  int lrow = lane & 15, lk = (lane >> 4) * 8, lr4 = (lane >> 4) * 4;
  {   // FFN GEMM1: M=16 N=512 K=128; wave owns 128 cols
    f32x4 acc[8];
#pragma unroll
    for (int nt = 0; nt < 8; ++nt) acc[nt] = zf;
#pragma unroll
    for (int kt = 0; kt < 4; ++kt) {
      bf16x8 a = *(const bf16x8*)&xln[lrow][kt * 32 + lk];
#pragma unroll
      for (int nt = 0; nt < 8; ++nt) {
        int nn = wid * 128 + nt * 16 + lrow;
        bf16x8 bfr = *(const bf16x8*)&w1t[nn * 128 + kt * 32 + lk];
        acc[nt] = MFMA16(a, bfr, acc[nt]);
      }
    }
#pragma unroll
    for (int nt = 0; nt < 8; ++nt) {
      int nn = wid * 128 + nt * 16 + lrow;
      float bias = b1[nn];
#pragma unroll
      for (int r = 0; r < 4; ++r)
        hid[lr4 + r][nn] = f2bf(fmaxf(acc[nt][r] + bias, 0.f));
    }
  }
  __syncthreads();
  {   // FFN GEMM2: M=16 N=128 K=512; wave owns 32 cols; e = hx + out + bias
    f32x4 acc2[2];
#pragma unroll
    for (int nt = 0; nt < 2; ++nt) acc2[nt] = zf;
#pragma unroll
    for (int kt = 0; kt < 16; ++kt) {
      bf16x8 a = *(const bf16x8*)&hid[lrow][kt * 32 + lk];
#pragma unroll
      for (int nt = 0; nt < 2; ++nt) {
        int nn = wid * 32 + nt * 16 + lrow;
        bf16x8 bfr = *(const bf16x8*)&w2t[nn * 512 + kt * 32 + lk];
        acc2[nt] = MFMA16(a, bfr, acc2[nt]);
      }
    }
#pragma unroll
    for (int nt = 0; nt < 2; ++nt) {
      int nn = wid * 32 + nt * 16 + lrow;
      float bias = b2[nn];
#pragma unroll
      for (int r = 0; r < 4; ++r)
        xln[lr4 + r][nn] = f2bf(hx[lr4 + r][nn] + acc2[nt][r] + bias);  // e
    }
  }
  __syncthreads();
  {   // MLP1: M=16 N=512 K=128 (e @ W1m + b1m, no relu) -> hid overlay
    f32x4 acc[8];
#pragma unroll
    for (int nt = 0; nt < 8; ++nt) acc[nt] = zf;
#pragma unroll
    for (int kt = 0; kt < 4; ++kt) {
      bf16x8 a = *(const bf16x8*)&xln[lrow][kt * 32 + lk];
#pragma unroll
      for (int nt = 0; nt < 8; ++nt) {
        int nn = wid * 128 + nt * 16 + lrow;
        bf16x8 bfr = *(const bf16x8*)&w1e[nn * 128 + kt * 32 + lk];
        acc[nt] = MFMA16(a, bfr, acc[nt]);
      }
    }
    __syncthreads();   // hid reads (GEMM2) done
#pragma unroll
    for (int nt = 0; nt < 8; ++nt) {
      int nn = wid * 128 + nt * 16 + lrow;
      float bias = b1m[nn];
#pragma unroll
      for (int r = 0; r < 4; ++r)
        hid[lr4 + r][nn] = f2bf(acc[nt][r] + bias);
    }
  }
  __syncthreads();
  {   // MLP2: M=16 N=128(120) K=512 -> out
    f32x4 acc2[2];
#pragma unroll
    for (int nt = 0; nt < 2; ++nt) acc2[nt] = zf;
#pragma unroll
    for (int kt = 0; kt < 16; ++kt) {
      bf16x8 a = *(const bf16x8*)&hid[lrow][kt * 32 + lk];
#pragma unroll
      for (int nt = 0; nt < 2; ++nt) {
        int nn = wid * 32 + nt * 16 + lrow;
        bf16x8 bfr = *(const bf16x8*)&w2e[nn * 512 + kt * 32 + lk];
        acc2[nt] = MFMA16(a, bfr, acc2[nt]);
      }
    }
#pragma unroll
    for (int nt = 0; nt < 2; ++nt) {
      int nn = wid * 32 + nt * 16 + lrow;
      if (nn < 120) {
        float bias = b2m[nn];
#pragma unroll
        for (int r = 0; r < 4; ++r)
          out[(base + lr4 + r) * 120 + nn] = acc2[nt][r] + bias;
      }
    }
  }
}

extern "C" void kernel_launch(void* const* d_in, const int* in_sizes, int n_in,
                              void* d_out, int out_size, void* d_ws, size_t ws_size,
                              hipStream_t stream) {
  const float* x        = (const float*)d_in[0];
  const void*  inv      = d_in[1];
  const float* emb_W    = (const float*)d_in[2];
  const float* emb_b    = (const float*)d_in[3];
  const float* dist_emb = (const float*)d_in[4];
  const float* ln_g     = (const float*)d_in[5];
  const float* ln_b     = (const float*)d_in[6];
  const float* Wq       = (const float*)d_in[7];
  const float* Wk       = (const float*)d_in[8];
  const float* Wv       = (const float*)d_in[9];
  const float* Wo       = (const float*)d_in[10];
  const float* ffn_W1   = (const float*)d_in[11];
  const float* ffn_b1   = (const float*)d_in[12];
  const float* ffn_W2   = (const float*)d_in[13];
  const float* ffn_b2   = (const float*)d_in[14];
  const float* mlp_W1   = (const float*)d_in[15];
  const float* mlp_b1   = (const float*)d_in[16];
  const float* mlp_W2   = (const float*)d_in[17];
  const float* mlp_b2   = (const float*)d_in[18];
  float* out = (float*)d_out;

  float* ws = (float*)d_ws;
  float* h  = ws;                                        // 10,240,000 floats
  unsigned short* wbf = (unsigned short*)(ws + 10240000);
  unsigned short* wqkv = wbf;                            // 196608
  unsigned short* wot  = wbf + 196608;                   // 65536
  unsigned short* w1t  = wbf + 262144;                   // 131072
  unsigned short* w2t  = wbf + 393216;                   // 131072
  unsigned short* w1e  = wbf + 524288;                   // 65536
  unsigned short* w2e  = wbf + 589824;                   // 65536 -> 655360
  int* flag = (int*)(ws + 10600000);

  detect_kernel<<<dim3(1), dim3(256), 0, stream>>>(inv, flag);
  convert_weights<<<dim3(640), dim3(256), 0, stream>>>(
      Wq, Wk, Wv, Wo, ffn_W1, ffn_W2, mlp_W1, mlp_W2,
      wqkv, wot, w1t, w2t, w1e, w2e);
  // layer 0 (full)
  temporal_attn_kernel<<<dim3(1600), dim3(512), 0, stream>>>(
      x, h, inv, flag, ln_g + 0 * DD, ln_b + 0 * DD, emb_W, emb_b,
      wqkv + 0 * 49152, wot + 0 * 16384, 1);
  social_attn_kernel<<<dim3(1600), dim3(512), 0, stream>>>(
      x, h, inv, flag, dist_emb, ln_g + 1 * DD, ln_b + 1 * DD,
      wqkv + 1 * 49152, wot + 1 * 16384, 0);
  ffn_kernel<<<dim3(2500), dim3(512), 0, stream>>>(
      h, ln_g + 2 * DD, ln_b + 2 * DD, w1t, ffn_b1, w2t, ffn_b2);
  // layer 1 (output slice: only agent-0 survives the tail)
  temporal_attn_kernel<<<dim3(1600), dim3(512), 0, stream>>>(
      x, h, inv, flag, ln_g + 3 * DD, ln_b + 3 * DD, emb_W, emb_b,
      wqkv + 2 * 49152, wot + 2 * 16384, 0);
  social_attn_kernel<<<dim3(1600), dim3(512), 0, stream>>>(
      x, h, inv, flag, dist_emb, ln_g + 4 * DD, ln_b + 4 * DD,
      wqkv + 3 * 49152, wot + 3 * 16384, 1);
  ffn_ego_kernel<<<dim3(100), dim3(256), 0, stream>>>(
      h, ln_g + 5 * DD, ln_b + 5 * DD,
      w1t + 65536, ffn_b1 + 512, w2t + 65536, ffn_b2 + 128,
      w1e, mlp_b1, w2e, mlp_b2, out);
}

// Round 13
// 369.169 us; speedup vs baseline: 1.9157x; 1.0854x over previous
//
#include <hip/hip_runtime.h>

// Decoder_36996848287748 v13 — v12 + memory-level-parallelism fixes:
//  * all weight-streaming loops preload fragment groups (4-8 in flight/wave)
//    via statically-indexed register arrays / double-buffered pipelines
//  * all LN phases batch their global h loads before the shuffle reduce
// Rationale: v12 counters showed ~26 GB/s/CU realized L2 BW == 1-2 loads in
// flight x 300ns latency. No numeric changes anywhere.
// Social shortcut: agents i>0 attend only to themselves => out_i = v_i (exact).
// MFMA 16x16x32_bf16: A[m=lane&15][k=(lane>>4)*8+e], B[n=lane&15][k=...],
// C[row=(lane>>4)*4+r][col=lane&15] (fp32 accum).

#define DD 128
typedef __attribute__((ext_vector_type(8))) short bf16x8;
typedef __attribute__((ext_vector_type(4))) float f32x4;
#define MFMA16(a, b, c) __builtin_amdgcn_mfma_f32_16x16x32_bf16(a, b, c, 0, 0, 0)

__device__ __forceinline__ float bf2f(unsigned short u) {
  union { unsigned int i; float f; } x; x.i = ((unsigned int)u) << 16; return x.f;
}
__device__ __forceinline__ unsigned short f2bf(float f) {
  union { float f; unsigned int i; } x; x.f = f;
  return (unsigned short)((x.i + 0x7FFFu + ((x.i >> 16) & 1u)) >> 16);
}
__device__ __forceinline__ float wave_sum(float v) {
#pragma unroll
  for (int off = 32; off > 0; off >>= 1) v += __shfl_xor(v, off, 64);
  return v;
}
__device__ __forceinline__ float wave_max(float v) {
#pragma unroll
  for (int off = 32; off > 0; off >>= 1) v = fmaxf(v, __shfl_xor(v, off, 64));
  return v;
}
__device__ __forceinline__ bool load_inv(const void* p, int idx, int bytemode) {
  if (bytemode) return ((const unsigned char*)p)[idx] != 0;
  return ((const int*)p)[idx] != 0;
}

__global__ void detect_kernel(const void* __restrict__ inv, int* __restrict__ flag) {
  __shared__ int found;
  if (threadIdx.x == 0) found = 0;
  __syncthreads();
  const unsigned char* p = (const unsigned char*)inv;
  int loc = 0;
  for (int i = threadIdx.x; i < 16384; i += blockDim.x)
    if ((i & 3) != 0 && p[i] != 0) loc = 1;
  if (loc) atomicOr(&found, 1);
  __syncthreads();
  if (threadIdx.x == 0) *flag = found ? 1 : 0;
}

// Transpose+cvt weights to bf16 [out][in] via 32x32 LDS tiles. 640 blocks.
__global__ __launch_bounds__(256) void convert_weights(
    const float* __restrict__ Wq, const float* __restrict__ Wk,
    const float* __restrict__ Wv, const float* __restrict__ Wo,
    const float* __restrict__ W1, const float* __restrict__ W2,
    const float* __restrict__ W1m, const float* __restrict__ W2m,
    unsigned short* __restrict__ wqkv, unsigned short* __restrict__ wot,
    unsigned short* __restrict__ w1t, unsigned short* __restrict__ w2t,
    unsigned short* __restrict__ w1e, unsigned short* __restrict__ w2e) {
  __shared__ float tile[32][33];
  int b = blockIdx.x;
  int tx = threadIdx.x & 31, ty = threadIdx.x >> 5;
  const float* src; unsigned short* dst;
  int o0, i0, srcld, dstld, osub = 0, obound = 1 << 30;
  if (b < 192) {                       // Wq/Wk/Wv -> wqkv[m][384][128]
    int m = b / 48, t2 = b % 48;
    o0 = (t2 / 4) * 32; i0 = (t2 % 4) * 32;
    int sel = o0 >> 7;
    src = (sel == 0 ? Wq : (sel == 1 ? Wk : Wv)) + m * 16384;
    osub = sel * 128; srcld = 128;
    dst = wqkv + m * 49152; dstld = 128;
  } else if (b < 256) {                // Wo -> wot[m][128][128]
    int m = (b - 192) / 16, t2 = (b - 192) % 16;
    o0 = (t2 / 4) * 32; i0 = (t2 % 4) * 32;
    src = Wo + m * 16384; srcld = 128;
    dst = wot + m * 16384; dstld = 128;
  } else if (b < 384) {                // W1 [128][512] -> w1t[l][512][128]
    int l = (b - 256) / 64, t2 = (b - 256) % 64;
    o0 = (t2 / 4) * 32; i0 = (t2 % 4) * 32;
    src = W1 + l * 65536; srcld = 512;
    dst = w1t + l * 65536; dstld = 128;
  } else if (b < 512) {                // W2 [512][128] -> w2t[l][128][512]
    int l = (b - 384) / 64, t2 = (b - 384) % 64;
    o0 = (t2 / 16) * 32; i0 = (t2 % 16) * 32;
    src = W2 + l * 65536; srcld = 128;
    dst = w2t + l * 65536; dstld = 512;
  } else if (b < 576) {                // mlp_W1 [128][512] -> w1e[512][128]
    int t2 = b - 512;
    o0 = (t2 / 4) * 32; i0 = (t2 % 4) * 32;
    src = W1m; srcld = 512;
    dst = w1e; dstld = 128;
  } else {                             // mlp_W2 [512][120] -> w2e[128][512] pad0
    int t2 = b - 576;
    o0 = (t2 / 16) * 32; i0 = (t2 % 16) * 32;
    src = W2m; srcld = 120; obound = 120;
    dst = w2e; dstld = 512;
  }
#pragma unroll
  for (int kk = 0; kk < 4; ++kk) {
    int i = i0 + ty + 8 * kk, o = o0 + tx;
    tile[ty + 8 * kk][tx] = (o < obound) ? src[i * srcld + (o - osub)] : 0.f;
  }
  __syncthreads();
#pragma unroll
  for (int kk = 0; kk < 4; ++kk) {
    int o = o0 + ty + 8 * kk, i = i0 + tx;
    dst[o * dstld + i] = f2bf(tile[tx][ty + 8 * kk]);
  }
}

// ---------------- Temporal attention v13 ----------------
__global__ __launch_bounds__(512, 4) void temporal_attn_kernel(
    const float* __restrict__ x, float* __restrict__ h,
    const void* __restrict__ inv, const int* __restrict__ flagp,
    const float* __restrict__ g, const float* __restrict__ bb,
    const float* __restrict__ embW, const float* __restrict__ embB,
    const unsigned short* __restrict__ wqkv,
    const unsigned short* __restrict__ wot, int first) {
  __shared__ __align__(16) unsigned short xbf[64][136];
  __shared__ __align__(16) unsigned short kbf[64][136];
  __shared__ __align__(16) unsigned short vT[128][72];     // V^T [d][tok]
  __shared__ __align__(16) unsigned short pbuf[8][16][72]; // P[tq_loc][tk] per head
  __shared__ float ssb[8][64];
  int seq = blockIdx.x;
  int tid = threadIdx.x, lane = tid & 63, wid = tid >> 6;
  unsigned long long invmask =
      __ballot((lane < 50) && load_inv(inv, seq * 50 + lane, *flagp));
  const f32x4 zf = (f32x4){0.f, 0.f, 0.f, 0.f};
  // --- P1: LN, batched global loads ---
  if (first) {
    for (int t = wid; t < 50; t += 8) {
      int tok = seq * 50 + t;
      float c0 = x[tok * 5], c1 = x[tok * 5 + 1], c2 = x[tok * 5 + 2];
      float c3 = x[tok * 5 + 3], c4 = x[tok * 5 + 4];
      float x0 = embB[lane] + c0 * embW[lane] + c1 * embW[128 + lane] +
                 c2 * embW[256 + lane] + c3 * embW[384 + lane] + c4 * embW[512 + lane];
      float x1 = embB[lane + 64] + c0 * embW[lane + 64] + c1 * embW[128 + lane + 64] +
                 c2 * embW[256 + lane + 64] + c3 * embW[384 + lane + 64] +
                 c4 * embW[512 + lane + 64];
      h[tok * DD + lane] = x0; h[tok * DD + lane + 64] = x1;
      float mu = wave_sum(x0 + x1) * (1.0f / 128.0f);
      float d0 = x0 - mu, d1 = x1 - mu;
      float var = wave_sum(d0 * d0 + d1 * d1) * (1.0f / 128.0f);
      float rstd = rsqrtf(var + 1e-5f);
      xbf[t][lane]      = f2bf(d0 * rstd * g[lane] + bb[lane]);
      xbf[t][lane + 64] = f2bf(d1 * rstd * g[lane + 64] + bb[lane + 64]);
    }
  } else {
    float v0[7], v1[7];
#pragma unroll
    for (int i = 0; i < 7; ++i) {
      int t = wid + 8 * i;
      if (t < 50) {
        v0[i] = h[(seq * 50 + t) * DD + lane];
        v1[i] = h[(seq * 50 + t) * DD + lane + 64];
      }
    }
#pragma unroll
    for (int i = 0; i < 7; ++i) {
      int t = wid + 8 * i;
      if (t < 50) {
        float mu = wave_sum(v0[i] + v1[i]) * (1.0f / 128.0f);
        float d0 = v0[i] - mu, d1 = v1[i] - mu;
        float var = wave_sum(d0 * d0 + d1 * d1) * (1.0f / 128.0f);
        float rstd = rsqrtf(var + 1e-5f);
        xbf[t][lane]      = f2bf(d0 * rstd * g[lane] + bb[lane]);
        xbf[t][lane + 64] = f2bf(d1 * rstd * g[lane + 64] + bb[lane + 64]);
      }
    }
  }
  for (int idx = tid; idx < 1904; idx += 512) {
    int r = idx / 136, cc = idx - r * 136;
    xbf[50 + r][cc] = 0;
    kbf[50 + r][cc] = 0;
  }
  for (int idx = tid; idx < 896; idx += 512) {
    int row = idx / 7, dwi = idx - row * 7;
    ((unsigned int*)&vT[row][50])[dwi] = 0u;
  }
  __syncthreads();
  int lrow = lane & 15, lk = (lane >> 4) * 8, lr4 = (lane >> 4) * 4;
  int colb = wid * 16 + lrow;
  // --- P2: QKV GEMM, per-pass weight preload (4 frags in flight) ---
  {   // K pass -> kbf
    f32x4 ac[4];
#pragma unroll
    for (int mt = 0; mt < 4; ++mt) ac[mt] = zf;
    bf16x8 wk[4];
#pragma unroll
    for (int kt = 0; kt < 4; ++kt)
      wk[kt] = *(const bf16x8*)&wqkv[((8 + wid) * 16 + lrow) * 128 + kt * 32 + lk];
#pragma unroll
    for (int kt = 0; kt < 4; ++kt)
#pragma unroll
      for (int mt = 0; mt < 4; ++mt) {
        bf16x8 a = *(const bf16x8*)&xbf[mt * 16 + lrow][kt * 32 + lk];
        ac[mt] = MFMA16(a, wk[kt], ac[mt]);
      }
#pragma unroll
    for (int mt = 0; mt < 4; ++mt)
#pragma unroll
      for (int r = 0; r < 4; ++r) {
        int row = mt * 16 + lr4 + r;
        if (row < 50) kbf[row][colb] = f2bf(ac[mt][r]);
      }
  }
  {   // V pass -> vT
    f32x4 ac[4];
#pragma unroll
    for (int mt = 0; mt < 4; ++mt) ac[mt] = zf;
    bf16x8 wv[4];
#pragma unroll
    for (int kt = 0; kt < 4; ++kt)
      wv[kt] = *(const bf16x8*)&wqkv[((16 + wid) * 16 + lrow) * 128 + kt * 32 + lk];
#pragma unroll
    for (int kt = 0; kt < 4; ++kt)
#pragma unroll
      for (int mt = 0; mt < 4; ++mt) {
        bf16x8 a = *(const bf16x8*)&xbf[mt * 16 + lrow][kt * 32 + lk];
        ac[mt] = MFMA16(a, wv[kt], ac[mt]);
      }
#pragma unroll
    for (int mt = 0; mt < 4; ++mt)
#pragma unroll
      for (int r = 0; r < 4; ++r) {
        int row = mt * 16 + lr4 + r;
        if (row < 50) vT[colb][row] = f2bf(ac[mt][r]);
      }
  }
  {   // Q pass: compute, sync, overlay into xbf
    f32x4 acQ[4];
#pragma unroll
    for (int mt = 0; mt < 4; ++mt) acQ[mt] = zf;
    bf16x8 wq[4];
#pragma unroll
    for (int kt = 0; kt < 4; ++kt)
      wq[kt] = *(const bf16x8*)&wqkv[(wid * 16 + lrow) * 128 + kt * 32 + lk];
#pragma unroll
    for (int kt = 0; kt < 4; ++kt)
#pragma unroll
      for (int mt = 0; mt < 4; ++mt) {
        bf16x8 a = *(const bf16x8*)&xbf[mt * 16 + lrow][kt * 32 + lk];
        acQ[mt] = MFMA16(a, wq[kt], acQ[mt]);
      }
    __syncthreads();
#pragma unroll
    for (int mt = 0; mt < 4; ++mt)
#pragma unroll
      for (int r = 0; r < 4; ++r) {
        int row = mt * 16 + lr4 + r;
        if (row < 50) xbf[row][colb] = f2bf(acQ[mt][r] * 0.25f);
      }
  }
  __syncthreads();
  // --- P3: MFMA attention (unchanged; same-wave LDS deps) ---
  {
    int hh = wid, c = lane & 15, gq = lane >> 4;
    const int hb = hh * 16;
    bf16x8 vfr0 = *(const bf16x8*)&vT[hb + c][gq * 8];
    bf16x8 vfr1 = *(const bf16x8*)&vT[hb + c][32 + gq * 8];
#pragma unroll
    for (int nt2 = 0; nt2 < 4; ++nt2) {
      bf16x8 qf = (bf16x8){0, 0, 0, 0, 0, 0, 0, 0};
      if (gq < 2) qf = *(const bf16x8*)&xbf[nt2 * 16 + c][hb + gq * 8];
      f32x4 Cs[4];
#pragma unroll
      for (int mt = 0; mt < 4; ++mt) {
        bf16x8 kf = (bf16x8){0, 0, 0, 0, 0, 0, 0, 0};
        if (gq < 2) kf = *(const bf16x8*)&kbf[mt * 16 + c][hb + gq * 8];
        Cs[mt] = MFMA16(kf, qf, zf);
      }
      int tq = nt2 * 16 + c;
      float ss = 0.f;
#pragma unroll
      for (int mt = 0; mt < 4; ++mt) {
        float pv[4];
#pragma unroll
        for (int r = 0; r < 4; ++r) {
          int tk = mt * 16 + gq * 4 + r;
          bool ok = (tk == tq) || ((tk < tq) && !((invmask >> tk) & 1ull));
          float p = ok ? __expf(Cs[mt][r]) : 0.f;
          ss += p;
          pv[r] = p;
        }
        unsigned int* dst = (unsigned int*)&pbuf[hh][c][mt * 16 + gq * 4];
        dst[0] = (unsigned)f2bf(pv[0]) | ((unsigned)f2bf(pv[1]) << 16);
        dst[1] = (unsigned)f2bf(pv[2]) | ((unsigned)f2bf(pv[3]) << 16);
      }
      ss += __shfl_xor(ss, 16, 64);
      ss += __shfl_xor(ss, 32, 64);
      if (gq == 0) ssb[hh][tq] = 1.f / ss;
      asm volatile("s_waitcnt lgkmcnt(0)" ::: "memory");
      __builtin_amdgcn_sched_barrier(0);
      bf16x8 pf0 = *(const bf16x8*)&pbuf[hh][c][gq * 8];
      bf16x8 pf1 = *(const bf16x8*)&pbuf[hh][c][32 + gq * 8];
      f32x4 acO = MFMA16(pf0, vfr0, zf);
      acO = MFMA16(pf1, vfr1, acO);
#pragma unroll
      for (int r = 0; r < 4; ++r) {
        int tqo = nt2 * 16 + gq * 4 + r;
        if (tqo < 50) {
          float rs = ssb[hh][tqo];
          xbf[tqo][hb + c] = f2bf(acO[r] * rs);
        }
      }
    }
  }
  __syncthreads();
  {   // P4: Wo + residual, weights preloaded
    f32x4 acc2[4];
#pragma unroll
    for (int mt = 0; mt < 4; ++mt) acc2[mt] = zf;
    bf16x8 wo4[4];
#pragma unroll
    for (int kt = 0; kt < 4; ++kt)
      wo4[kt] = *(const bf16x8*)&wot[(wid * 16 + lrow) * 128 + kt * 32 + lk];
#pragma unroll
    for (int kt = 0; kt < 4; ++kt)
#pragma unroll
      for (int mt = 0; mt < 4; ++mt) {
        bf16x8 a = *(const bf16x8*)&xbf[mt * 16 + lrow][kt * 32 + lk];
        acc2[mt] = MFMA16(a, wo4[kt], acc2[mt]);
      }
#pragma unroll
    for (int mt = 0; mt < 4; ++mt)
#pragma unroll
      for (int r = 0; r < 4; ++r) {
        int row = mt * 16 + lr4 + r;
        if (row < 50) h[(seq * 50 + row) * DD + colb] += acc2[mt][r];
      }
  }
}

// ---------------- Social attention v13 (ego_only mode kept) ----------------
__global__ __launch_bounds__(512, 6) void social_attn_kernel(
    const float* __restrict__ x, float* __restrict__ h,
    const void* __restrict__ inv, const int* __restrict__ flagp,
    const float* __restrict__ dist_emb,
    const float* __restrict__ g, const float* __restrict__ bb,
    const unsigned short* __restrict__ wqkv,
    const unsigned short* __restrict__ wot, int ego_only) {
  __shared__ __align__(16) unsigned short xbf[64][136];  // LN-out -> K overlay
  __shared__ __align__(16) unsigned short vsb[64][136];  // V; row0 -> ego attn
  __shared__ float q0s[128];
  __shared__ float aw[8][52];
  int nt_ = blockIdx.x;
  int n = nt_ / 50, t = nt_ - n * 50;
  int tid = threadIdx.x, lane = tid & 63, wid = tid >> 6;
  const f32x4 zf = (f32x4){0.f, 0.f, 0.f, 0.f};
  {   // LN, batched loads
    float v0[7], v1[7];
#pragma unroll
    for (int i = 0; i < 7; ++i) {
      int j = wid + 8 * i;
      if (j < 50) {
        int tok = (n * 50 + j) * 50 + t;
        v0[i] = h[tok * DD + lane];
        v1[i] = h[tok * DD + lane + 64];
      }
    }
#pragma unroll
    for (int i = 0; i < 7; ++i) {
      int j = wid + 8 * i;
      if (j < 50) {
        float mu = wave_sum(v0[i] + v1[i]) * (1.0f / 128.0f);
        float d0 = v0[i] - mu, d1 = v1[i] - mu;
        float var = wave_sum(d0 * d0 + d1 * d1) * (1.0f / 128.0f);
        float rstd = rsqrtf(var + 1e-5f);
        xbf[j][lane]      = f2bf(d0 * rstd * g[lane] + bb[lane]);
        xbf[j][lane + 64] = f2bf(d1 * rstd * g[lane + 64] + bb[lane + 64]);
      }
    }
  }
  __syncthreads();
  int lrow = lane & 15, lk = (lane >> 4) * 8, lr4 = (lane >> 4) * 4;
  int colb = wid * 16 + lrow;
  {   // V pass -> vsb (weights preloaded)
    f32x4 ac[4];
#pragma unroll
    for (int mt = 0; mt < 4; ++mt) ac[mt] = zf;
    bf16x8 wv[4];
#pragma unroll
    for (int kt = 0; kt < 4; ++kt)
      wv[kt] = *(const bf16x8*)&wqkv[((16 + wid) * 16 + lrow) * 128 + kt * 32 + lk];
#pragma unroll
    for (int kt = 0; kt < 4; ++kt)
#pragma unroll
      for (int mt = 0; mt < 4; ++mt) {
        bf16x8 a = *(const bf16x8*)&xbf[mt * 16 + lrow][kt * 32 + lk];
        ac[mt] = MFMA16(a, wv[kt], ac[mt]);
      }
#pragma unroll
    for (int mt = 0; mt < 4; ++mt)
#pragma unroll
      for (int r = 0; r < 4; ++r) {
        int row = mt * 16 + lr4 + r;
        if (row < 50) vsb[row][colb] = f2bf(ac[mt][r]);
      }
  }
  {   // Q pass (ego row only)
    f32x4 acq = zf;
    bf16x8 wq[4];
#pragma unroll
    for (int kt = 0; kt < 4; ++kt)
      wq[kt] = *(const bf16x8*)&wqkv[(wid * 16 + lrow) * 128 + kt * 32 + lk];
#pragma unroll
    for (int kt = 0; kt < 4; ++kt) {
      bf16x8 a0 = *(const bf16x8*)&xbf[lrow][kt * 32 + lk];
      acq = MFMA16(a0, wq[kt], acq);
    }
    if (lane < 16) q0s[wid * 16 + lane] = acq[0];
  }
  {   // K pass: compute, sync, overlay into xbf
    f32x4 ac[4];
#pragma unroll
    for (int mt = 0; mt < 4; ++mt) ac[mt] = zf;
    bf16x8 wk[4];
#pragma unroll
    for (int kt = 0; kt < 4; ++kt)
      wk[kt] = *(const bf16x8*)&wqkv[((8 + wid) * 16 + lrow) * 128 + kt * 32 + lk];
#pragma unroll
    for (int kt = 0; kt < 4; ++kt)
#pragma unroll
      for (int mt = 0; mt < 4; ++mt) {
        bf16x8 a = *(const bf16x8*)&xbf[mt * 16 + lrow][kt * 32 + lk];
        ac[mt] = MFMA16(a, wk[kt], ac[mt]);
      }
    __syncthreads();
#pragma unroll
    for (int mt = 0; mt < 4; ++mt)
#pragma unroll
      for (int r = 0; r < 4; ++r) {
        int row = mt * 16 + lr4 + r;
        if (row < 50) xbf[row][colb] = f2bf(ac[mt][r]);
      }
  }
  __syncthreads();
  {   // ego softmax; wave = head, lane = agent j
    int hh = wid, j = lane;
    float s = -1e30f;
    if (j < 50) {
      float x0 = x[(n * 2500 + t) * 5 + 0];
      float y0 = x[(n * 2500 + t) * 5 + 1];
      int tokj = (n * 50 + j) * 50 + t;
      float xj = x[tokj * 5 + 0], yj = x[tokj * 5 + 1];
      float dx = x0 - xj, dy = y0 - yj;
      float dist = sqrtf(dx * dx + dy * dy);
      int bucket = (int)(dist / 1.5625f);
      bucket = bucket < 0 ? 0 : (bucket > 31 ? 31 : bucket);
      bool mk = (j != 0) && ((dist > 50.0f) || load_inv(inv, tokj, *flagp));
      bf16x8 k0 = *(const bf16x8*)&xbf[j][hh * 16];
      bf16x8 k1 = *(const bf16x8*)&xbf[j][hh * 16 + 8];
      float acc2 = 0.f;
#pragma unroll
      for (int u = 0; u < 8; ++u)
        acc2 += q0s[hh * 16 + u] * bf2f((unsigned short)k0[u]) +
                q0s[hh * 16 + 8 + u] * bf2f((unsigned short)k1[u]);
      s = mk ? -1e9f : acc2 * 0.25f + dist_emb[bucket * 8 + hh];
    }
    float m = wave_max(s);
    float p = (j < 50) ? __expf(s - m) : 0.f;
    float sm = wave_sum(p);
    if (j < 50) aw[hh][j] = p / sm;
  }
  __syncthreads();
  float a0val = 0.f;
  if (tid < 128) {
    int hh2 = tid >> 4;
#pragma unroll 10
    for (int j = 0; j < 50; ++j) a0val += aw[hh2][j] * bf2f(vsb[j][tid]);
  }
  __syncthreads();
  if (tid < 128) vsb[0][tid] = f2bf(a0val);
  __syncthreads();
  if (!ego_only) {   // Wo + residual, all rows (weights preloaded)
    f32x4 acc2[4];
#pragma unroll
    for (int mt = 0; mt < 4; ++mt) acc2[mt] = zf;
    bf16x8 wo4[4];
#pragma unroll
    for (int kt = 0; kt < 4; ++kt)
      wo4[kt] = *(const bf16x8*)&wot[(wid * 16 + lrow) * 128 + kt * 32 + lk];
#pragma unroll
    for (int kt = 0; kt < 4; ++kt)
#pragma unroll
      for (int mt = 0; mt < 4; ++mt) {
        bf16x8 a = *(const bf16x8*)&vsb[mt * 16 + lrow][kt * 32 + lk];
        acc2[mt] = MFMA16(a, wo4[kt], acc2[mt]);
      }
#pragma unroll
    for (int mt = 0; mt < 4; ++mt)
#pragma unroll
      for (int r = 0; r < 4; ++r) {
        int row = mt * 16 + lr4 + r;
        if (row < 50)
          h[((n * 50 + row) * 50 + t) * DD + colb] += acc2[mt][r];
      }
  } else {           // Wo + residual for row 0 only
    f32x4 acc2 = zf;
    bf16x8 wo4[4];
#pragma unroll
    for (int kt = 0; kt < 4; ++kt)
      wo4[kt] = *(const bf16x8*)&wot[(wid * 16 + lrow) * 128 + kt * 32 + lk];
#pragma unroll
    for (int kt = 0; kt < 4; ++kt) {
      bf16x8 a = *(const bf16x8*)&vsb[lrow][kt * 32 + lk];
      acc2 = MFMA16(a, wo4[kt], acc2);
    }
    if ((lane >> 4) == 0)
      h[(n * 2500 + t) * DD + colb] += acc2[0];
  }
}

// ---------------- FFN v13: weight double-buffer pipeline ----------------
__global__ __launch_bounds__(512, 6) void ffn_kernel(
    float* __restrict__ h, const float* __restrict__ g, const float* __restrict__ bb,
    const unsigned short* __restrict__ w1t, const float* __restrict__ b1,
    const unsigned short* __restrict__ w2t, const float* __restrict__ b2) {
  __shared__ __align__(16) unsigned short xbf[32][136];
  __shared__ __align__(16) unsigned short hid[32][520];
  int base = blockIdx.x * 32;
  int tid = threadIdx.x, lane = tid & 63, wid = tid >> 6;
  {   // LN, batched loads (4 rounds)
    float v0[4], v1[4];
#pragma unroll
    for (int i = 0; i < 4; ++i) {
      int tok = base + wid + 8 * i;
      v0[i] = h[tok * DD + lane];
      v1[i] = h[tok * DD + lane + 64];
    }
#pragma unroll
    for (int i = 0; i < 4; ++i) {
      int r = wid + 8 * i;
      float mu = wave_sum(v0[i] + v1[i]) * (1.0f / 128.0f);
      float d0 = v0[i] - mu, d1 = v1[i] - mu;
      float var = wave_sum(d0 * d0 + d1 * d1) * (1.0f / 128.0f);
      float rstd = rsqrtf(var + 1e-5f);
      xbf[r][lane]      = f2bf(d0 * rstd * g[lane] + bb[lane]);
      xbf[r][lane + 64] = f2bf(d1 * rstd * g[lane + 64] + bb[lane + 64]);
    }
  }
  __syncthreads();
  int lrow = lane & 15, lk = (lane >> 4) * 8, lr4 = (lane >> 4) * 4;
  // GEMM1: M=32 N=512 K=128; wave owns 64 cols; weights 1-kt-ahead pipeline
  {
    f32x4 acc[2][4];
#pragma unroll
    for (int mt = 0; mt < 2; ++mt)
#pragma unroll
      for (int nt = 0; nt < 4; ++nt) acc[mt][nt] = (f32x4){0.f, 0.f, 0.f, 0.f};
    bf16x8 w[2][4];
#pragma unroll
    for (int nt = 0; nt < 4; ++nt)
      w[0][nt] = *(const bf16x8*)&w1t[(wid * 64 + nt * 16 + lrow) * 128 + lk];
#pragma unroll
    for (int kt = 0; kt < 4; ++kt) {
      if (kt < 3) {
#pragma unroll
        for (int nt = 0; nt < 4; ++nt)
          w[(kt + 1) & 1][nt] =
              *(const bf16x8*)&w1t[(wid * 64 + nt * 16 + lrow) * 128 + (kt + 1) * 32 + lk];
      }
      bf16x8 a0 = *(const bf16x8*)&xbf[lrow][kt * 32 + lk];
      bf16x8 a1 = *(const bf16x8*)&xbf[16 + lrow][kt * 32 + lk];
#pragma unroll
      for (int nt = 0; nt < 4; ++nt) {
        acc[0][nt] = MFMA16(a0, w[kt & 1][nt], acc[0][nt]);
        acc[1][nt] = MFMA16(a1, w[kt & 1][nt], acc[1][nt]);
      }
    }
#pragma unroll
    for (int nt = 0; nt < 4; ++nt) {
      int nn = wid * 64 + nt * 16 + lrow;
      float bias = b1[nn];
#pragma unroll
      for (int mt = 0; mt < 2; ++mt)
#pragma unroll
        for (int r = 0; r < 4; ++r)
          hid[mt * 16 + lr4 + r][nn] = f2bf(fmaxf(acc[mt][nt][r] + bias, 0.f));
    }
  }
  __syncthreads();
  // GEMM2: M=32 N=128 K=512; wave owns 16 cols; weight groups of 4, 1 ahead
  {
    f32x4 acc2[2];
#pragma unroll
    for (int mt = 0; mt < 2; ++mt) acc2[mt] = (f32x4){0.f, 0.f, 0.f, 0.f};
    int nn = wid * 16 + lrow;
    bf16x8 w[2][4];
#pragma unroll
    for (int kk = 0; kk < 4; ++kk)
      w[0][kk] = *(const bf16x8*)&w2t[nn * 512 + kk * 32 + lk];
#pragma unroll
    for (int gph = 0; gph < 4; ++gph) {
      if (gph < 3) {
#pragma unroll
        for (int kk = 0; kk < 4; ++kk)
          w[(gph + 1) & 1][kk] =
              *(const bf16x8*)&w2t[nn * 512 + ((gph + 1) * 4 + kk) * 32 + lk];
      }
#pragma unroll
      for (int kk = 0; kk < 4; ++kk) {
        int kt = gph * 4 + kk;
        bf16x8 a0 = *(const bf16x8*)&hid[lrow][kt * 32 + lk];
        bf16x8 a1 = *(const bf16x8*)&hid[16 + lrow][kt * 32 + lk];
        acc2[0] = MFMA16(a0, w[gph & 1][kk], acc2[0]);
        acc2[1] = MFMA16(a1, w[gph & 1][kk], acc2[1]);
      }
    }
    float bias = b2[nn];
#pragma unroll
    for (int mt = 0; mt < 2; ++mt)
#pragma unroll
      for (int r = 0; r < 4; ++r)
        h[(base + mt * 16 + lr4 + r) * DD + nn] += acc2[mt][r] + bias;
  }
}

// ---------------- Fused layer-1 FFN (agent-0 only) + ego MLP ----------------
__global__ __launch_bounds__(256) void ffn_ego_kernel(
    const float* __restrict__ h,
    const float* __restrict__ g2, const float* __restrict__ bb2,
    const unsigned short* __restrict__ w1t, const float* __restrict__ b1,
    const unsigned short* __restrict__ w2t, const float* __restrict__ b2,
    const unsigned short* __restrict__ w1e, const float* __restrict__ b1m,
    const unsigned short* __restrict__ w2e, const float* __restrict__ b2m,
    float* __restrict__ out) {
  __shared__ float hx[16][132];
  __shared__ __align__(16) unsigned short xln[16][136];
  __shared__ __align__(16) unsigned short hid[16][520];
  int base = blockIdx.x * 16;
  int tid = threadIdx.x, lane = tid & 63, wid = tid >> 6;
  const f32x4 zf = (f32x4){0.f, 0.f, 0.f, 0.f};
  for (int idx = tid; idx < 2048; idx += 256) {
    int r = idx >> 7, d = idx & 127;
    int nt = base + r, n = nt / 50, t = nt - n * 50;
    hx[r][d] = h[(n * 2500 + t) * DD + d];
  }
  __syncthreads();
  for (int r = wid; r < 16; r += 4) {
    float x0 = hx[r][lane], x1 = hx[r][lane + 64];
    float mu = wave_sum(x0 + x1) * (1.0f / 128.0f);
    float d0 = x0 - mu, d1 = x1 - mu;
    float var = wave_sum(d0 * d0 + d1 * d1) * (1.0f / 128.0f);
    float rstd = rsqrtf(var + 1e-5f);
    xln[r][lane]      = f2bf(d0 * rstd * g2[lane] + bb2[lane]);
    xln[r][lane + 64] = f2bf(d1 * rstd * g2[lane + 64] + bb2[lane + 64]);
  }
  __syncthreads();
  int lrow = lane & 15, lk = (lane >> 4) * 8, lr4 = (lane >> 4) * 4;
  {   // FFN GEMM1
    f32x4 acc[8];
#pragma unroll
    for (int nt = 0; nt < 8; ++nt) acc[nt] = zf;
#pragma unroll
    for (int kt = 0; kt < 4; ++kt) {
      bf16x8 a = *(const bf16x8*)&xln[lrow][kt * 32 + lk];
#pragma unroll
      for (int nt = 0; nt < 8; ++nt) {
        int nn = wid * 128 + nt * 16 + lrow;
        bf16x8 bfr = *(const bf16x8*)&w1t[nn * 128 + kt * 32 + lk];
        acc[nt] = MFMA16(a, bfr, acc[nt]);
      }
    }
#pragma unroll
    for (int nt = 0; nt < 8; ++nt) {
      int nn = wid * 128 + nt * 16 + lrow;
      float bias = b1[nn];
#pragma unroll
      for (int r = 0; r < 4; ++r)
        hid[lr4 + r][nn] = f2bf(fmaxf(acc[nt][r] + bias, 0.f));
    }
  }
  __syncthreads();
  {   // FFN GEMM2 -> e
    f32x4 acc2[2];
#pragma unroll
    for (int nt = 0; nt < 2; ++nt) acc2[nt] = zf;
#pragma unroll
    for (int kt = 0; kt < 16; ++kt) {
      bf16x8 a = *(const bf16x8*)&hid[lrow][kt * 32 + lk];
#pragma unroll
      for (int nt = 0; nt < 2; ++nt) {
        int nn = wid * 32 + nt * 16 + lrow;
        bf16x8 bfr = *(const bf16x8*)&w2t[nn * 512 + kt * 32 + lk];
        acc2[nt] = MFMA16(a, bfr, acc2[nt]);
      }
    }
#pragma unroll
    for (int nt = 0; nt < 2; ++nt) {
      int nn = wid * 32 + nt * 16 + lrow;
      float bias = b2[nn];
#pragma unroll
      for (int r = 0; r < 4; ++r)
        xln[lr4 + r][nn] = f2bf(hx[lr4 + r][nn] + acc2[nt][r] + bias);
    }
  }
  __syncthreads();
  {   // MLP1
    f32x4 acc[8];
#pragma unroll
    for (int nt = 0; nt < 8; ++nt) acc[nt] = zf;
#pragma unroll
    for (int kt = 0; kt < 4; ++kt) {
      bf16x8 a = *(const bf16x8*)&xln[lrow][kt * 32 + lk];
#pragma unroll
      for (int nt = 0; nt < 8; ++nt) {
        int nn = wid * 128 + nt * 16 + lrow;
        bf16x8 bfr = *(const bf16x8*)&w1e[nn * 128 + kt * 32 + lk];
        acc[nt] = MFMA16(a, bfr, acc[nt]);
      }
    }
    __syncthreads();
#pragma unroll
    for (int nt = 0; nt < 8; ++nt) {
      int nn = wid * 128 + nt * 16 + lrow;
      float bias = b1m[nn];
#pragma unroll
      for (int r = 0; r < 4; ++r)
        hid[lr4 + r][nn] = f2bf(acc[nt][r] + bias);
    }
  }
  __syncthreads();
  {   // MLP2 -> out
    f32x4 acc2[2];
#pragma unroll
    for (int nt = 0; nt < 2; ++nt) acc2[nt] = zf;
#pragma unroll
    for (int kt = 0; kt < 16; ++kt) {
      bf16x8 a = *(const bf16x8*)&hid[lrow][kt * 32 + lk];
#pragma unroll
      for (int nt = 0; nt < 2; ++nt) {
        int nn = wid * 32 + nt * 16 + lrow;
        bf16x8 bfr = *(const bf16x8*)&w2e[nn * 512 + kt * 32 + lk];
        acc2[nt] = MFMA16(a, bfr, acc2[nt]);
      }
    }
#pragma unroll
    for (int nt = 0; nt < 2; ++nt) {
      int nn = wid * 32 + nt * 16 + lrow;
      if (nn < 120) {
        float bias = b2m[nn];
#pragma unroll
        for (int r = 0; r < 4; ++r)
          out[(base + lr4 + r) * 120 + nn] = acc2[nt][r] + bias;
      }
    }
  }
}

extern "C" void kernel_launch(void* const* d_in, const int* in_sizes, int n_in,
                              void* d_out, int out_size, void* d_ws, size_t ws_size,
                              hipStream_t stream) {
  const float* x        = (const float*)d_in[0];
  const void*  inv      = d_in[1];
  const float* emb_W    = (const float*)d_in[2];
  const float* emb_b    = (const float*)d_in[3];
  const float* dist_emb = (const float*)d_in[4];
  const float* ln_g     = (const float*)d_in[5];
  const float* ln_b     = (const float*)d_in[6];
  const float* Wq       = (const float*)d_in[7];
  const float* Wk       = (const float*)d_in[8];
  const float* Wv       = (const float*)d_in[9];
  const float* Wo       = (const float*)d_in[10];
  const float* ffn_W1   = (const float*)d_in[11];
  const float* ffn_b1   = (const float*)d_in[12];
  const float* ffn_W2   = (const float*)d_in[13];
  const float* ffn_b2   = (const float*)d_in[14];
  const float* mlp_W1   = (const float*)d_in[15];
  const float* mlp_b1   = (const float*)d_in[16];
  const float* mlp_W2   = (const float*)d_in[17];
  const float* mlp_b2   = (const float*)d_in[18];
  float* out = (float*)d_out;

  float* ws = (float*)d_ws;
  float* h  = ws;                                        // 10,240,000 floats
  unsigned short* wbf = (unsigned short*)(ws + 10240000);
  unsigned short* wqkv = wbf;                            // 196608
  unsigned short* wot  = wbf + 196608;                   // 65536
  unsigned short* w1t  = wbf + 262144;                   // 131072
  unsigned short* w2t  = wbf + 393216;                   // 131072
  unsigned short* w1e  = wbf + 524288;                   // 65536
  unsigned short* w2e  = wbf + 589824;                   // 65536 -> 655360
  int* flag = (int*)(ws + 10600000);

  detect_kernel<<<dim3(1), dim3(256), 0, stream>>>(inv, flag);
  convert_weights<<<dim3(640), dim3(256), 0, stream>>>(
      Wq, Wk, Wv, Wo, ffn_W1, ffn_W2, mlp_W1, mlp_W2,
      wqkv, wot, w1t, w2t, w1e, w2e);
  // layer 0 (full)
  temporal_attn_kernel<<<dim3(1600), dim3(512), 0, stream>>>(
      x, h, inv, flag, ln_g + 0 * DD, ln_b + 0 * DD, emb_W, emb_b,
      wqkv + 0 * 49152, wot + 0 * 16384, 1);
  social_attn_kernel<<<dim3(1600), dim3(512), 0, stream>>>(
      x, h, inv, flag, dist_emb, ln_g + 1 * DD, ln_b + 1 * DD,
      wqkv + 1 * 49152, wot + 1 * 16384, 0);
  ffn_kernel<<<dim3(2500), dim3(512), 0, stream>>>(
      h, ln_g + 2 * DD, ln_b + 2 * DD, w1t, ffn_b1, w2t, ffn_b2);
  // layer 1 (output slice: only agent-0 survives the tail)
  temporal_attn_kernel<<<dim3(1600), dim3(512), 0, stream>>>(
      x, h, inv, flag, ln_g + 3 * DD, ln_b + 3 * DD, emb_W, emb_b,
      wqkv + 2 * 49152, wot + 2 * 16384, 0);
  social_attn_kernel<<<dim3(1600), dim3(512), 0, stream>>>(
      x, h, inv, flag, dist_emb, ln_g + 4 * DD, ln_b + 4 * DD,
      wqkv + 3 * 49152, wot + 3 * 16384, 1);
  ffn_ego_kernel<<<dim3(100), dim3(256), 0, stream>>>(
      h, ln_g + 5 * DD, ln_b + 5 * DD,
      w1t + 65536, ffn_b1 + 512, w2t + 65536, ffn_b2 + 128,
      w1e, mlp_b1, w2e, mlp_b2, out);
}

// Round 14
// 338.668 us; speedup vs baseline: 2.0882x; 1.0901x over previous
//
#include <hip/hip_runtime.h>

// Decoder_36996848287748 v14 — v13 + ffn M=64 (halve L2 weight traffic).
// v13 post-mortem: ffn VGPR=40 -> compiler collapsed the reg double-buffer;
// v9->v10 wave-doubling gave only +14% -> ffn is L2-traffic-bound, not
// latency-bound. Fix: 64 tokens/block (1250 blocks) amortize the 256KB
// weight stream over 2x tokens. hid[64] bf16 66.6KB + reused xbf 8.7KB
// -> 75.3KB LDS, 2 blocks/CU. Bit-identical math.
// Social shortcut: agents i>0 attend only to themselves => out_i = v_i (exact).
// MFMA 16x16x32_bf16: A[m=lane&15][k=(lane>>4)*8+e], B[n=lane&15][k=...],
// C[row=(lane>>4)*4+r][col=lane&15] (fp32 accum).

#define DD 128
typedef __attribute__((ext_vector_type(8))) short bf16x8;
typedef __attribute__((ext_vector_type(4))) float f32x4;
#define MFMA16(a, b, c) __builtin_amdgcn_mfma_f32_16x16x32_bf16(a, b, c, 0, 0, 0)

__device__ __forceinline__ float bf2f(unsigned short u) {
  union { unsigned int i; float f; } x; x.i = ((unsigned int)u) << 16; return x.f;
}
__device__ __forceinline__ unsigned short f2bf(float f) {
  union { float f; unsigned int i; } x; x.f = f;
  return (unsigned short)((x.i + 0x7FFFu + ((x.i >> 16) & 1u)) >> 16);
}
__device__ __forceinline__ float wave_sum(float v) {
#pragma unroll
  for (int off = 32; off > 0; off >>= 1) v += __shfl_xor(v, off, 64);
  return v;
}
__device__ __forceinline__ float wave_max(float v) {
#pragma unroll
  for (int off = 32; off > 0; off >>= 1) v = fmaxf(v, __shfl_xor(v, off, 64));
  return v;
}
__device__ __forceinline__ bool load_inv(const void* p, int idx, int bytemode) {
  if (bytemode) return ((const unsigned char*)p)[idx] != 0;
  return ((const int*)p)[idx] != 0;
}

__global__ void detect_kernel(const void* __restrict__ inv, int* __restrict__ flag) {
  __shared__ int found;
  if (threadIdx.x == 0) found = 0;
  __syncthreads();
  const unsigned char* p = (const unsigned char*)inv;
  int loc = 0;
  for (int i = threadIdx.x; i < 16384; i += blockDim.x)
    if ((i & 3) != 0 && p[i] != 0) loc = 1;
  if (loc) atomicOr(&found, 1);
  __syncthreads();
  if (threadIdx.x == 0) *flag = found ? 1 : 0;
}

// Transpose+cvt weights to bf16 [out][in] via 32x32 LDS tiles. 640 blocks.
__global__ __launch_bounds__(256) void convert_weights(
    const float* __restrict__ Wq, const float* __restrict__ Wk,
    const float* __restrict__ Wv, const float* __restrict__ Wo,
    const float* __restrict__ W1, const float* __restrict__ W2,
    const float* __restrict__ W1m, const float* __restrict__ W2m,
    unsigned short* __restrict__ wqkv, unsigned short* __restrict__ wot,
    unsigned short* __restrict__ w1t, unsigned short* __restrict__ w2t,
    unsigned short* __restrict__ w1e, unsigned short* __restrict__ w2e) {
  __shared__ float tile[32][33];
  int b = blockIdx.x;
  int tx = threadIdx.x & 31, ty = threadIdx.x >> 5;
  const float* src; unsigned short* dst;
  int o0, i0, srcld, dstld, osub = 0, obound = 1 << 30;
  if (b < 192) {                       // Wq/Wk/Wv -> wqkv[m][384][128]
    int m = b / 48, t2 = b % 48;
    o0 = (t2 / 4) * 32; i0 = (t2 % 4) * 32;
    int sel = o0 >> 7;
    src = (sel == 0 ? Wq : (sel == 1 ? Wk : Wv)) + m * 16384;
    osub = sel * 128; srcld = 128;
    dst = wqkv + m * 49152; dstld = 128;
  } else if (b < 256) {                // Wo -> wot[m][128][128]
    int m = (b - 192) / 16, t2 = (b - 192) % 16;
    o0 = (t2 / 4) * 32; i0 = (t2 % 4) * 32;
    src = Wo + m * 16384; srcld = 128;
    dst = wot + m * 16384; dstld = 128;
  } else if (b < 384) {                // W1 [128][512] -> w1t[l][512][128]
    int l = (b - 256) / 64, t2 = (b - 256) % 64;
    o0 = (t2 / 4) * 32; i0 = (t2 % 4) * 32;
    src = W1 + l * 65536; srcld = 512;
    dst = w1t + l * 65536; dstld = 128;
  } else if (b < 512) {                // W2 [512][128] -> w2t[l][128][512]
    int l = (b - 384) / 64, t2 = (b - 384) % 64;
    o0 = (t2 / 16) * 32; i0 = (t2 % 16) * 32;
    src = W2 + l * 65536; srcld = 128;
    dst = w2t + l * 65536; dstld = 512;
  } else if (b < 576) {                // mlp_W1 [128][512] -> w1e[512][128]
    int t2 = b - 512;
    o0 = (t2 / 4) * 32; i0 = (t2 % 4) * 32;
    src = W1m; srcld = 512;
    dst = w1e; dstld = 128;
  } else {                             // mlp_W2 [512][120] -> w2e[128][512] pad0
    int t2 = b - 576;
    o0 = (t2 / 16) * 32; i0 = (t2 % 16) * 32;
    src = W2m; srcld = 120; obound = 120;
    dst = w2e; dstld = 512;
  }
#pragma unroll
  for (int kk = 0; kk < 4; ++kk) {
    int i = i0 + ty + 8 * kk, o = o0 + tx;
    tile[ty + 8 * kk][tx] = (o < obound) ? src[i * srcld + (o - osub)] : 0.f;
  }
  __syncthreads();
#pragma unroll
  for (int kk = 0; kk < 4; ++kk) {
    int o = o0 + ty + 8 * kk, i = i0 + tx;
    dst[o * dstld + i] = f2bf(tile[tx][ty + 8 * kk]);
  }
}

// ---------------- Temporal attention (unchanged from v13) ----------------
__global__ __launch_bounds__(512, 4) void temporal_attn_kernel(
    const float* __restrict__ x, float* __restrict__ h,
    const void* __restrict__ inv, const int* __restrict__ flagp,
    const float* __restrict__ g, const float* __restrict__ bb,
    const float* __restrict__ embW, const float* __restrict__ embB,
    const unsigned short* __restrict__ wqkv,
    const unsigned short* __restrict__ wot, int first) {
  __shared__ __align__(16) unsigned short xbf[64][136];
  __shared__ __align__(16) unsigned short kbf[64][136];
  __shared__ __align__(16) unsigned short vT[128][72];     // V^T [d][tok]
  __shared__ __align__(16) unsigned short pbuf[8][16][72]; // P[tq_loc][tk] per head
  __shared__ float ssb[8][64];
  int seq = blockIdx.x;
  int tid = threadIdx.x, lane = tid & 63, wid = tid >> 6;
  unsigned long long invmask =
      __ballot((lane < 50) && load_inv(inv, seq * 50 + lane, *flagp));
  const f32x4 zf = (f32x4){0.f, 0.f, 0.f, 0.f};
  if (first) {
    for (int t = wid; t < 50; t += 8) {
      int tok = seq * 50 + t;
      float c0 = x[tok * 5], c1 = x[tok * 5 + 1], c2 = x[tok * 5 + 2];
      float c3 = x[tok * 5 + 3], c4 = x[tok * 5 + 4];
      float x0 = embB[lane] + c0 * embW[lane] + c1 * embW[128 + lane] +
                 c2 * embW[256 + lane] + c3 * embW[384 + lane] + c4 * embW[512 + lane];
      float x1 = embB[lane + 64] + c0 * embW[lane + 64] + c1 * embW[128 + lane + 64] +
                 c2 * embW[256 + lane + 64] + c3 * embW[384 + lane + 64] +
                 c4 * embW[512 + lane + 64];
      h[tok * DD + lane] = x0; h[tok * DD + lane + 64] = x1;
      float mu = wave_sum(x0 + x1) * (1.0f / 128.0f);
      float d0 = x0 - mu, d1 = x1 - mu;
      float var = wave_sum(d0 * d0 + d1 * d1) * (1.0f / 128.0f);
      float rstd = rsqrtf(var + 1e-5f);
      xbf[t][lane]      = f2bf(d0 * rstd * g[lane] + bb[lane]);
      xbf[t][lane + 64] = f2bf(d1 * rstd * g[lane + 64] + bb[lane + 64]);
    }
  } else {
    float v0[7], v1[7];
#pragma unroll
    for (int i = 0; i < 7; ++i) {
      int t = wid + 8 * i;
      if (t < 50) {
        v0[i] = h[(seq * 50 + t) * DD + lane];
        v1[i] = h[(seq * 50 + t) * DD + lane + 64];
      }
    }
#pragma unroll
    for (int i = 0; i < 7; ++i) {
      int t = wid + 8 * i;
      if (t < 50) {
        float mu = wave_sum(v0[i] + v1[i]) * (1.0f / 128.0f);
        float d0 = v0[i] - mu, d1 = v1[i] - mu;
        float var = wave_sum(d0 * d0 + d1 * d1) * (1.0f / 128.0f);
        float rstd = rsqrtf(var + 1e-5f);
        xbf[t][lane]      = f2bf(d0 * rstd * g[lane] + bb[lane]);
        xbf[t][lane + 64] = f2bf(d1 * rstd * g[lane + 64] + bb[lane + 64]);
      }
    }
  }
  for (int idx = tid; idx < 1904; idx += 512) {
    int r = idx / 136, cc = idx - r * 136;
    xbf[50 + r][cc] = 0;
    kbf[50 + r][cc] = 0;
  }
  for (int idx = tid; idx < 896; idx += 512) {
    int row = idx / 7, dwi = idx - row * 7;
    ((unsigned int*)&vT[row][50])[dwi] = 0u;
  }
  __syncthreads();
  int lrow = lane & 15, lk = (lane >> 4) * 8, lr4 = (lane >> 4) * 4;
  int colb = wid * 16 + lrow;
  {   // K pass -> kbf
    f32x4 ac[4];
#pragma unroll
    for (int mt = 0; mt < 4; ++mt) ac[mt] = zf;
    bf16x8 wk[4];
#pragma unroll
    for (int kt = 0; kt < 4; ++kt)
      wk[kt] = *(const bf16x8*)&wqkv[((8 + wid) * 16 + lrow) * 128 + kt * 32 + lk];
#pragma unroll
    for (int kt = 0; kt < 4; ++kt)
#pragma unroll
      for (int mt = 0; mt < 4; ++mt) {
        bf16x8 a = *(const bf16x8*)&xbf[mt * 16 + lrow][kt * 32 + lk];
        ac[mt] = MFMA16(a, wk[kt], ac[mt]);
      }
#pragma unroll
    for (int mt = 0; mt < 4; ++mt)
#pragma unroll
      for (int r = 0; r < 4; ++r) {
        int row = mt * 16 + lr4 + r;
        if (row < 50) kbf[row][colb] = f2bf(ac[mt][r]);
      }
  }
  {   // V pass -> vT
    f32x4 ac[4];
#pragma unroll
    for (int mt = 0; mt < 4; ++mt) ac[mt] = zf;
    bf16x8 wv[4];
#pragma unroll
    for (int kt = 0; kt < 4; ++kt)
      wv[kt] = *(const bf16x8*)&wqkv[((16 + wid) * 16 + lrow) * 128 + kt * 32 + lk];
#pragma unroll
    for (int kt = 0; kt < 4; ++kt)
#pragma unroll
      for (int mt = 0; mt < 4; ++mt) {
        bf16x8 a = *(const bf16x8*)&xbf[mt * 16 + lrow][kt * 32 + lk];
        ac[mt] = MFMA16(a, wv[kt], ac[mt]);
      }
#pragma unroll
    for (int mt = 0; mt < 4; ++mt)
#pragma unroll
      for (int r = 0; r < 4; ++r) {
        int row = mt * 16 + lr4 + r;
        if (row < 50) vT[colb][row] = f2bf(ac[mt][r]);
      }
  }
  {   // Q pass: compute, sync, overlay into xbf
    f32x4 acQ[4];
#pragma unroll
    for (int mt = 0; mt < 4; ++mt) acQ[mt] = zf;
    bf16x8 wq[4];
#pragma unroll
    for (int kt = 0; kt < 4; ++kt)
      wq[kt] = *(const bf16x8*)&wqkv[(wid * 16 + lrow) * 128 + kt * 32 + lk];
#pragma unroll
    for (int kt = 0; kt < 4; ++kt)
#pragma unroll
      for (int mt = 0; mt < 4; ++mt) {
        bf16x8 a = *(const bf16x8*)&xbf[mt * 16 + lrow][kt * 32 + lk];
        acQ[mt] = MFMA16(a, wq[kt], acQ[mt]);
      }
    __syncthreads();
#pragma unroll
    for (int mt = 0; mt < 4; ++mt)
#pragma unroll
      for (int r = 0; r < 4; ++r) {
        int row = mt * 16 + lr4 + r;
        if (row < 50) xbf[row][colb] = f2bf(acQ[mt][r] * 0.25f);
      }
  }
  __syncthreads();
  {   // P3: MFMA attention (same-wave LDS deps)
    int hh = wid, c = lane & 15, gq = lane >> 4;
    const int hb = hh * 16;
    bf16x8 vfr0 = *(const bf16x8*)&vT[hb + c][gq * 8];
    bf16x8 vfr1 = *(const bf16x8*)&vT[hb + c][32 + gq * 8];
#pragma unroll
    for (int nt2 = 0; nt2 < 4; ++nt2) {
      bf16x8 qf = (bf16x8){0, 0, 0, 0, 0, 0, 0, 0};
      if (gq < 2) qf = *(const bf16x8*)&xbf[nt2 * 16 + c][hb + gq * 8];
      f32x4 Cs[4];
#pragma unroll
      for (int mt = 0; mt < 4; ++mt) {
        bf16x8 kf = (bf16x8){0, 0, 0, 0, 0, 0, 0, 0};
        if (gq < 2) kf = *(const bf16x8*)&kbf[mt * 16 + c][hb + gq * 8];
        Cs[mt] = MFMA16(kf, qf, zf);
      }
      int tq = nt2 * 16 + c;
      float ss = 0.f;
#pragma unroll
      for (int mt = 0; mt < 4; ++mt) {
        float pv[4];
#pragma unroll
        for (int r = 0; r < 4; ++r) {
          int tk = mt * 16 + gq * 4 + r;
          bool ok = (tk == tq) || ((tk < tq) && !((invmask >> tk) & 1ull));
          float p = ok ? __expf(Cs[mt][r]) : 0.f;
          ss += p;
          pv[r] = p;
        }
        unsigned int* dst = (unsigned int*)&pbuf[hh][c][mt * 16 + gq * 4];
        dst[0] = (unsigned)f2bf(pv[0]) | ((unsigned)f2bf(pv[1]) << 16);
        dst[1] = (unsigned)f2bf(pv[2]) | ((unsigned)f2bf(pv[3]) << 16);
      }
      ss += __shfl_xor(ss, 16, 64);
      ss += __shfl_xor(ss, 32, 64);
      if (gq == 0) ssb[hh][tq] = 1.f / ss;
      asm volatile("s_waitcnt lgkmcnt(0)" ::: "memory");
      __builtin_amdgcn_sched_barrier(0);
      bf16x8 pf0 = *(const bf16x8*)&pbuf[hh][c][gq * 8];
      bf16x8 pf1 = *(const bf16x8*)&pbuf[hh][c][32 + gq * 8];
      f32x4 acO = MFMA16(pf0, vfr0, zf);
      acO = MFMA16(pf1, vfr1, acO);
#pragma unroll
      for (int r = 0; r < 4; ++r) {
        int tqo = nt2 * 16 + gq * 4 + r;
        if (tqo < 50) {
          float rs = ssb[hh][tqo];
          xbf[tqo][hb + c] = f2bf(acO[r] * rs);
        }
      }
    }
  }
  __syncthreads();
  {   // P4: Wo + residual, weights preloaded
    f32x4 acc2[4];
#pragma unroll
    for (int mt = 0; mt < 4; ++mt) acc2[mt] = zf;
    bf16x8 wo4[4];
#pragma unroll
    for (int kt = 0; kt < 4; ++kt)
      wo4[kt] = *(const bf16x8*)&wot[(wid * 16 + lrow) * 128 + kt * 32 + lk];
#pragma unroll
    for (int kt = 0; kt < 4; ++kt)
#pragma unroll
      for (int mt = 0; mt < 4; ++mt) {
        bf16x8 a = *(const bf16x8*)&xbf[mt * 16 + lrow][kt * 32 + lk];
        acc2[mt] = MFMA16(a, wo4[kt], acc2[mt]);
      }
#pragma unroll
    for (int mt = 0; mt < 4; ++mt)
#pragma unroll
      for (int r = 0; r < 4; ++r) {
        int row = mt * 16 + lr4 + r;
        if (row < 50) h[(seq * 50 + row) * DD + colb] += acc2[mt][r];
      }
  }
}

// ---------------- Social attention (unchanged from v13) ----------------
__global__ __launch_bounds__(512, 6) void social_attn_kernel(
    const float* __restrict__ x, float* __restrict__ h,
    const void* __restrict__ inv, const int* __restrict__ flagp,
    const float* __restrict__ dist_emb,
    const float* __restrict__ g, const float* __restrict__ bb,
    const unsigned short* __restrict__ wqkv,
    const unsigned short* __restrict__ wot, int ego_only) {
  __shared__ __align__(16) unsigned short xbf[64][136];
  __shared__ __align__(16) unsigned short vsb[64][136];
  __shared__ float q0s[128];
  __shared__ float aw[8][52];
  int nt_ = blockIdx.x;
  int n = nt_ / 50, t = nt_ - n * 50;
  int tid = threadIdx.x, lane = tid & 63, wid = tid >> 6;
  const f32x4 zf = (f32x4){0.f, 0.f, 0.f, 0.f};
  {
    float v0[7], v1[7];
#pragma unroll
    for (int i = 0; i < 7; ++i) {
      int j = wid + 8 * i;
      if (j < 50) {
        int tok = (n * 50 + j) * 50 + t;
        v0[i] = h[tok * DD + lane];
        v1[i] = h[tok * DD + lane + 64];
      }
    }
#pragma unroll
    for (int i = 0; i < 7; ++i) {
      int j = wid + 8 * i;
      if (j < 50) {
        float mu = wave_sum(v0[i] + v1[i]) * (1.0f / 128.0f);
        float d0 = v0[i] - mu, d1 = v1[i] - mu;
        float var = wave_sum(d0 * d0 + d1 * d1) * (1.0f / 128.0f);
        float rstd = rsqrtf(var + 1e-5f);
        xbf[j][lane]      = f2bf(d0 * rstd * g[lane] + bb[lane]);
        xbf[j][lane + 64] = f2bf(d1 * rstd * g[lane + 64] + bb[lane + 64]);
      }
    }
  }
  __syncthreads();
  int lrow = lane & 15, lk = (lane >> 4) * 8, lr4 = (lane >> 4) * 4;
  int colb = wid * 16 + lrow;
  {   // V pass -> vsb
    f32x4 ac[4];
#pragma unroll
    for (int mt = 0; mt < 4; ++mt) ac[mt] = zf;
    bf16x8 wv[4];
#pragma unroll
    for (int kt = 0; kt < 4; ++kt)
      wv[kt] = *(const bf16x8*)&wqkv[((16 + wid) * 16 + lrow) * 128 + kt * 32 + lk];
#pragma unroll
    for (int kt = 0; kt < 4; ++kt)
#pragma unroll
      for (int mt = 0; mt < 4; ++mt) {
        bf16x8 a = *(const bf16x8*)&xbf[mt * 16 + lrow][kt * 32 + lk];
        ac[mt] = MFMA16(a, wv[kt], ac[mt]);
      }
#pragma unroll
    for (int mt = 0; mt < 4; ++mt)
#pragma unroll
      for (int r = 0; r < 4; ++r) {
        int row = mt * 16 + lr4 + r;
        if (row < 50) vsb[row][colb] = f2bf(ac[mt][r]);
      }
  }
  {   // Q pass (ego row only)
    f32x4 acq = zf;
    bf16x8 wq[4];
#pragma unroll
    for (int kt = 0; kt < 4; ++kt)
      wq[kt] = *(const bf16x8*)&wqkv[(wid * 16 + lrow) * 128 + kt * 32 + lk];
#pragma unroll
    for (int kt = 0; kt < 4; ++kt) {
      bf16x8 a0 = *(const bf16x8*)&xbf[lrow][kt * 32 + lk];
      acq = MFMA16(a0, wq[kt], acq);
    }
    if (lane < 16) q0s[wid * 16 + lane] = acq[0];
  }
  {   // K pass: compute, sync, overlay into xbf
    f32x4 ac[4];
#pragma unroll
    for (int mt = 0; mt < 4; ++mt) ac[mt] = zf;
    bf16x8 wk[4];
#pragma unroll
    for (int kt = 0; kt < 4; ++kt)
      wk[kt] = *(const bf16x8*)&wqkv[((8 + wid) * 16 + lrow) * 128 + kt * 32 + lk];
#pragma unroll
    for (int kt = 0; kt < 4; ++kt)
#pragma unroll
      for (int mt = 0; mt < 4; ++mt) {
        bf16x8 a = *(const bf16x8*)&xbf[mt * 16 + lrow][kt * 32 + lk];
        ac[mt] = MFMA16(a, wk[kt], ac[mt]);
      }
    __syncthreads();
#pragma unroll
    for (int mt = 0; mt < 4; ++mt)
#pragma unroll
      for (int r = 0; r < 4; ++r) {
        int row = mt * 16 + lr4 + r;
        if (row < 50) xbf[row][colb] = f2bf(ac[mt][r]);
      }
  }
  __syncthreads();
  {   // ego softmax; wave = head, lane = agent j
    int hh = wid, j = lane;
    float s = -1e30f;
    if (j < 50) {
      float x0 = x[(n * 2500 + t) * 5 + 0];
      float y0 = x[(n * 2500 + t) * 5 + 1];
      int tokj = (n * 50 + j) * 50 + t;
      float xj = x[tokj * 5 + 0], yj = x[tokj * 5 + 1];
      float dx = x0 - xj, dy = y0 - yj;
      float dist = sqrtf(dx * dx + dy * dy);
      int bucket = (int)(dist / 1.5625f);
      bucket = bucket < 0 ? 0 : (bucket > 31 ? 31 : bucket);
      bool mk = (j != 0) && ((dist > 50.0f) || load_inv(inv, tokj, *flagp));
      bf16x8 k0 = *(const bf16x8*)&xbf[j][hh * 16];
      bf16x8 k1 = *(const bf16x8*)&xbf[j][hh * 16 + 8];
      float acc2 = 0.f;
#pragma unroll
      for (int u = 0; u < 8; ++u)
        acc2 += q0s[hh * 16 + u] * bf2f((unsigned short)k0[u]) +
                q0s[hh * 16 + 8 + u] * bf2f((unsigned short)k1[u]);
      s = mk ? -1e9f : acc2 * 0.25f + dist_emb[bucket * 8 + hh];
    }
    float m = wave_max(s);
    float p = (j < 50) ? __expf(s - m) : 0.f;
    float sm = wave_sum(p);
    if (j < 50) aw[hh][j] = p / sm;
  }
  __syncthreads();
  float a0val = 0.f;
  if (tid < 128) {
    int hh2 = tid >> 4;
#pragma unroll 10
    for (int j = 0; j < 50; ++j) a0val += aw[hh2][j] * bf2f(vsb[j][tid]);
  }
  __syncthreads();
  if (tid < 128) vsb[0][tid] = f2bf(a0val);
  __syncthreads();
  if (!ego_only) {
    f32x4 acc2[4];
#pragma unroll
    for (int mt = 0; mt < 4; ++mt) acc2[mt] = zf;
    bf16x8 wo4[4];
#pragma unroll
    for (int kt = 0; kt < 4; ++kt)
      wo4[kt] = *(const bf16x8*)&wot[(wid * 16 + lrow) * 128 + kt * 32 + lk];
#pragma unroll
    for (int kt = 0; kt < 4; ++kt)
#pragma unroll
      for (int mt = 0; mt < 4; ++mt) {
        bf16x8 a = *(const bf16x8*)&vsb[mt * 16 + lrow][kt * 32 + lk];
        acc2[mt] = MFMA16(a, wo4[kt], acc2[mt]);
      }
#pragma unroll
    for (int mt = 0; mt < 4; ++mt)
#pragma unroll
      for (int r = 0; r < 4; ++r) {
        int row = mt * 16 + lr4 + r;
        if (row < 50)
          h[((n * 50 + row) * 50 + t) * DD + colb] += acc2[mt][r];
      }
  } else {
    f32x4 acc2 = zf;
    bf16x8 wo4[4];
#pragma unroll
    for (int kt = 0; kt < 4; ++kt)
      wo4[kt] = *(const bf16x8*)&wot[(wid * 16 + lrow) * 128 + kt * 32 + lk];
#pragma unroll
    for (int kt = 0; kt < 4; ++kt) {
      bf16x8 a = *(const bf16x8*)&vsb[lrow][kt * 32 + lk];
      acc2 = MFMA16(a, wo4[kt], acc2);
    }
    if ((lane >> 4) == 0)
      h[(n * 2500 + t) * DD + colb] += acc2[0];
  }
}

// ---------------- FFN v14: M=64 tokens/block, halved L2 weight traffic ----------------
// 512 thr / 8 waves. LDS = xbf 8,704 + hid 66,560 = 75,264B -> 2 blocks/CU.
__global__ __launch_bounds__(512, 4) void ffn_kernel(
    float* __restrict__ h, const float* __restrict__ g, const float* __restrict__ bb,
    const unsigned short* __restrict__ w1t, const float* __restrict__ b1,
    const unsigned short* __restrict__ w2t, const float* __restrict__ b2) {
  __shared__ __align__(16) unsigned short xbf[32][136];   // reused per subtile
  __shared__ __align__(16) unsigned short hid[64][520];
  int base = blockIdx.x * 64;
  int tid = threadIdx.x, lane = tid & 63, wid = tid >> 6;
  int lrow = lane & 15, lk = (lane >> 4) * 8, lr4 = (lane >> 4) * 4;
#pragma unroll 1
  for (int s = 0; s < 2; ++s) {
    int tb = base + s * 32;
    {   // LN rows tb..tb+31, batched loads
      float v0[4], v1[4];
#pragma unroll
      for (int i = 0; i < 4; ++i) {
        int tok = tb + wid + 8 * i;
        v0[i] = h[tok * DD + lane];
        v1[i] = h[tok * DD + lane + 64];
      }
#pragma unroll
      for (int i = 0; i < 4; ++i) {
        int r = wid + 8 * i;
        float mu = wave_sum(v0[i] + v1[i]) * (1.0f / 128.0f);
        float d0 = v0[i] - mu, d1 = v1[i] - mu;
        float var = wave_sum(d0 * d0 + d1 * d1) * (1.0f / 128.0f);
        float rstd = rsqrtf(var + 1e-5f);
        xbf[r][lane]      = f2bf(d0 * rstd * g[lane] + bb[lane]);
        xbf[r][lane + 64] = f2bf(d1 * rstd * g[lane + 64] + bb[lane + 64]);
      }
    }
    __syncthreads();
    // GEMM1 subtile: M=32 N=512 K=128; wave owns 64 cols
    {
      f32x4 acc[2][4];
#pragma unroll
      for (int mt = 0; mt < 2; ++mt)
#pragma unroll
        for (int nt = 0; nt < 4; ++nt) acc[mt][nt] = (f32x4){0.f, 0.f, 0.f, 0.f};
#pragma unroll
      for (int kt = 0; kt < 4; ++kt) {
        bf16x8 a0 = *(const bf16x8*)&xbf[lrow][kt * 32 + lk];
        bf16x8 a1 = *(const bf16x8*)&xbf[16 + lrow][kt * 32 + lk];
#pragma unroll
        for (int nt = 0; nt < 4; ++nt) {
          int nn = wid * 64 + nt * 16 + lrow;
          bf16x8 bfr = *(const bf16x8*)&w1t[nn * 128 + kt * 32 + lk];
          acc[0][nt] = MFMA16(a0, bfr, acc[0][nt]);
          acc[1][nt] = MFMA16(a1, bfr, acc[1][nt]);
        }
      }
#pragma unroll
      for (int nt = 0; nt < 4; ++nt) {
        int nn = wid * 64 + nt * 16 + lrow;
        float bias = b1[nn];
#pragma unroll
        for (int mt = 0; mt < 2; ++mt)
#pragma unroll
          for (int r = 0; r < 4; ++r)
            hid[s * 32 + mt * 16 + lr4 + r][nn] =
                f2bf(fmaxf(acc[mt][nt][r] + bias, 0.f));
      }
    }
    __syncthreads();   // xbf reuse next subtile / hid complete before GEMM2
  }
  // GEMM2: M=64 N=128 K=512; wave owns 16 cols
  {
    f32x4 acc2[4];
#pragma unroll
    for (int mt = 0; mt < 4; ++mt) acc2[mt] = (f32x4){0.f, 0.f, 0.f, 0.f};
    int nn = wid * 16 + lrow;
#pragma unroll
    for (int kt = 0; kt < 16; ++kt) {
      bf16x8 bfr = *(const bf16x8*)&w2t[nn * 512 + kt * 32 + lk];
#pragma unroll
      for (int mt = 0; mt < 4; ++mt) {
        bf16x8 a = *(const bf16x8*)&hid[mt * 16 + lrow][kt * 32 + lk];
        acc2[mt] = MFMA16(a, bfr, acc2[mt]);
      }
    }
    float bias = b2[nn];
#pragma unroll
    for (int mt = 0; mt < 4; ++mt)
#pragma unroll
      for (int r = 0; r < 4; ++r)
        h[(base + mt * 16 + lr4 + r) * DD + nn] += acc2[mt][r] + bias;
  }
}

// ---------------- Fused layer-1 FFN (agent-0 only) + ego MLP ----------------
__global__ __launch_bounds__(256) void ffn_ego_kernel(
    const float* __restrict__ h,
    const float* __restrict__ g2, const float* __restrict__ bb2,
    const unsigned short* __restrict__ w1t, const float* __restrict__ b1,
    const unsigned short* __restrict__ w2t, const float* __restrict__ b2,
    const unsigned short* __restrict__ w1e, const float* __restrict__ b1m,
    const unsigned short* __restrict__ w2e, const float* __restrict__ b2m,
    float* __restrict__ out) {
  __shared__ float hx[16][132];
  __shared__ __align__(16) unsigned short xln[16][136];
  __shared__ __align__(16) unsigned short hid[16][520];
  int base = blockIdx.x * 16;
  int tid = threadIdx.x, lane = tid & 63, wid = tid >> 6;
  const f32x4 zf = (f32x4){0.f, 0.f, 0.f, 0.f};
  for (int idx = tid; idx < 2048; idx += 256) {
    int r = idx >> 7, d = idx & 127;
    int nt = base + r, n = nt / 50, t = nt - n * 50;
    hx[r][d] = h[(n * 2500 + t) * DD + d];
  }
  __syncthreads();
  for (int r = wid; r < 16; r += 4) {
    float x0 = hx[r][lane], x1 = hx[r][lane + 64];
    float mu = wave_sum(x0 + x1) * (1.0f / 128.0f);
    float d0 = x0 - mu, d1 = x1 - mu;
    float var = wave_sum(d0 * d0 + d1 * d1) * (1.0f / 128.0f);
    float rstd = rsqrtf(var + 1e-5f);
    xln[r][lane]      = f2bf(d0 * rstd * g2[lane] + bb2[lane]);
    xln[r][lane + 64] = f2bf(d1 * rstd * g2[lane + 64] + bb2[lane + 64]);
  }
  __syncthreads();
  int lrow = lane & 15, lk = (lane >> 4) * 8, lr4 = (lane >> 4) * 4;
  {   // FFN GEMM1
    f32x4 acc[8];
#pragma unroll
    for (int nt = 0; nt < 8; ++nt) acc[nt] = zf;
#pragma unroll
    for (int kt = 0; kt < 4; ++kt) {
      bf16x8 a = *(const bf16x8*)&xln[lrow][kt * 32 + lk];
#pragma unroll
      for (int nt = 0; nt < 8; ++nt) {
        int nn = wid * 128 + nt * 16 + lrow;
        bf16x8 bfr = *(const bf16x8*)&w1t[nn * 128 + kt * 32 + lk];
        acc[nt] = MFMA16(a, bfr, acc[nt]);
      }
    }
#pragma unroll
    for (int nt = 0; nt < 8; ++nt) {
      int nn = wid * 128 + nt * 16 + lrow;
      float bias = b1[nn];
#pragma unroll
      for (int r = 0; r < 4; ++r)
        hid[lr4 + r][nn] = f2bf(fmaxf(acc[nt][r] + bias, 0.f));
    }
  }
  __syncthreads();
  {   // FFN GEMM2 -> e
    f32x4 acc2[2];
#pragma unroll
    for (int nt = 0; nt < 2; ++nt) acc2[nt] = zf;
#pragma unroll
    for (int kt = 0; kt < 16; ++kt) {
      bf16x8 a = *(const bf16x8*)&hid[lrow][kt * 32 + lk];
#pragma unroll
      for (int nt = 0; nt < 2; ++nt) {
        int nn = wid * 32 + nt * 16 + lrow;
        bf16x8 bfr = *(const bf16x8*)&w2t[nn * 512 + kt * 32 + lk];
        acc2[nt] = MFMA16(a, bfr, acc2[nt]);
      }
    }
#pragma unroll
    for (int nt = 0; nt < 2; ++nt) {
      int nn = wid * 32 + nt * 16 + lrow;
      float bias = b2[nn];
#pragma unroll
      for (int r = 0; r < 4; ++r)
        xln[lr4 + r][nn] = f2bf(hx[lr4 + r][nn] + acc2[nt][r] + bias);
    }
  }
  __syncthreads();
  {   // MLP1
    f32x4 acc[8];
#pragma unroll
    for (int nt = 0; nt < 8; ++nt) acc[nt] = zf;
#pragma unroll
    for (int kt = 0; kt < 4; ++kt) {
      bf16x8 a = *(const bf16x8*)&xln[lrow][kt * 32 + lk];
#pragma unroll
      for (int nt = 0; nt < 8; ++nt) {
        int nn = wid * 128 + nt * 16 + lrow;
        bf16x8 bfr = *(const bf16x8*)&w1e[nn * 128 + kt * 32 + lk];
        acc[nt] = MFMA16(a, bfr, acc[nt]);
      }
    }
    __syncthreads();
#pragma unroll
    for (int nt = 0; nt < 8; ++nt) {
      int nn = wid * 128 + nt * 16 + lrow;
      float bias = b1m[nn];
#pragma unroll
      for (int r = 0; r < 4; ++r)
        hid[lr4 + r][nn] = f2bf(acc[nt][r] + bias);
    }
  }
  __syncthreads();
  {   // MLP2 -> out
    f32x4 acc2[2];
#pragma unroll
    for (int nt = 0; nt < 2; ++nt) acc2[nt] = zf;
#pragma unroll
    for (int kt = 0; kt < 16; ++kt) {
      bf16x8 a = *(const bf16x8*)&hid[lrow][kt * 32 + lk];
#pragma unroll
      for (int nt = 0; nt < 2; ++nt) {
        int nn = wid * 32 + nt * 16 + lrow;
        bf16x8 bfr = *(const bf16x8*)&w2e[nn * 512 + kt * 32 + lk];
        acc2[nt] = MFMA16(a, bfr, acc2[nt]);
      }
    }
#pragma unroll
    for (int nt = 0; nt < 2; ++nt) {
      int nn = wid * 32 + nt * 16 + lrow;
      if (nn < 120) {
        float bias = b2m[nn];
#pragma unroll
        for (int r = 0; r < 4; ++r)
          out[(base + lr4 + r) * 120 + nn] = acc2[nt][r] + bias;
      }
    }
  }
}

extern "C" void kernel_launch(void* const* d_in, const int* in_sizes, int n_in,
                              void* d_out, int out_size, void* d_ws, size_t ws_size,
                              hipStream_t stream) {
  const float* x        = (const float*)d_in[0];
  const void*  inv      = d_in[1];
  const float* emb_W    = (const float*)d_in[2];
  const float* emb_b    = (const float*)d_in[3];
  const float* dist_emb = (const float*)d_in[4];
  const float* ln_g     = (const float*)d_in[5];
  const float* ln_b     = (const float*)d_in[6];
  const float* Wq       = (const float*)d_in[7];
  const float* Wk       = (const float*)d_in[8];
  const float* Wv       = (const float*)d_in[9];
  const float* Wo       = (const float*)d_in[10];
  const float* ffn_W1   = (const float*)d_in[11];
  const float* ffn_b1   = (const float*)d_in[12];
  const float* ffn_W2   = (const float*)d_in[13];
  const float* ffn_b2   = (const float*)d_in[14];
  const float* mlp_W1   = (const float*)d_in[15];
  const float* mlp_b1   = (const float*)d_in[16];
  const float* mlp_W2   = (const float*)d_in[17];
  const float* mlp_b2   = (const float*)d_in[18];
  float* out = (float*)d_out;

  float* ws = (float*)d_ws;
  float* h  = ws;                                        // 10,240,000 floats
  unsigned short* wbf = (unsigned short*)(ws + 10240000);
  unsigned short* wqkv = wbf;                            // 196608
  unsigned short* wot  = wbf + 196608;                   // 65536
  unsigned short* w1t  = wbf + 262144;                   // 131072
  unsigned short* w2t  = wbf + 393216;                   // 131072
  unsigned short* w1e  = wbf + 524288;                   // 65536
  unsigned short* w2e  = wbf + 589824;                   // 65536 -> 655360
  int* flag = (int*)(ws + 10600000);

  detect_kernel<<<dim3(1), dim3(256), 0, stream>>>(inv, flag);
  convert_weights<<<dim3(640), dim3(256), 0, stream>>>(
      Wq, Wk, Wv, Wo, ffn_W1, ffn_W2, mlp_W1, mlp_W2,
      wqkv, wot, w1t, w2t, w1e, w2e);
  // layer 0 (full)
  temporal_attn_kernel<<<dim3(1600), dim3(512), 0, stream>>>(
      x, h, inv, flag, ln_g + 0 * DD, ln_b + 0 * DD, emb_W, emb_b,
      wqkv + 0 * 49152, wot + 0 * 16384, 1);
  social_attn_kernel<<<dim3(1600), dim3(512), 0, stream>>>(
      x, h, inv, flag, dist_emb, ln_g + 1 * DD, ln_b + 1 * DD,
      wqkv + 1 * 49152, wot + 1 * 16384, 0);
  ffn_kernel<<<dim3(1250), dim3(512), 0, stream>>>(
      h, ln_g + 2 * DD, ln_b + 2 * DD, w1t, ffn_b1, w2t, ffn_b2);
  // layer 1 (output slice: only agent-0 survives the tail)
  temporal_attn_kernel<<<dim3(1600), dim3(512), 0, stream>>>(
      x, h, inv, flag, ln_g + 3 * DD, ln_b + 3 * DD, emb_W, emb_b,
      wqkv + 2 * 49152, wot + 2 * 16384, 0);
  social_attn_kernel<<<dim3(1600), dim3(512), 0, stream>>>(
      x, h, inv, flag, dist_emb, ln_g + 4 * DD, ln_b + 4 * DD,
      wqkv + 3 * 49152, wot + 3 * 16384, 1);
  ffn_ego_kernel<<<dim3(100), dim3(256), 0, stream>>>(
      h, ln_g + 5 * DD, ln_b + 5 * DD,
      w1t + 65536, ffn_b1 + 512, w2t + 65536, ffn_b2 + 128,
      w1e, mlp_b1, w2e, mlp_b2, out);
}